// Round 2
// baseline (1464.830 us; speedup 1.0000x reference)
//
#include <hip/hip_runtime.h>
#include <cstdint>
#include <cstddef>

#define HN    4096
#define TT    128
#define NIN   1024
#define NOUTC 256
#define NWGH  64
#define NWGO  4
#define NWGT  (NWGH + NWGO)

// ---------------- device-wide sense-reversing barrier (bounded spin) --------
__device__ __forceinline__ void gridbar(unsigned* bar, unsigned nwg, unsigned& lsense) {
    __syncthreads();
    if (threadIdx.x == 0) {
        unsigned s = lsense ^ 1u;
        lsense = s;
        __threadfence();
        unsigned prev = __hip_atomic_fetch_add(&bar[0], 1u, __ATOMIC_ACQ_REL, __HIP_MEMORY_SCOPE_AGENT);
        if (prev == nwg - 1u) {
            __hip_atomic_store(&bar[0], 0u, __ATOMIC_RELAXED, __HIP_MEMORY_SCOPE_AGENT);
            __hip_atomic_store(&bar[1], s, __ATOMIC_RELEASE, __HIP_MEMORY_SCOPE_AGENT);
        } else {
            int budget = 1 << 18;   // bounded: never hang the GPU
            while (__hip_atomic_load(&bar[1], __ATOMIC_ACQUIRE, __HIP_MEMORY_SCOPE_AGENT) != s) {
                __builtin_amdgcn_s_sleep(1);
                if (--budget == 0) break;
            }
        }
        __threadfence();
    }
    __syncthreads();
}

// -------- K1: eff = recurrent*mask*binary (into d_out rec region) + zero sync span
__global__ __launch_bounds__(256) void k_eff_zero(
    const float4* __restrict__ r4, const float4* __restrict__ m4,
    const float4* __restrict__ b4, float4* __restrict__ e4,
    unsigned* __restrict__ zbase, int zwords)
{
    if (blockIdx.x == gridDim.x - 1) {
        for (int i = threadIdx.x; i < zwords; i += 256) zbase[i] = 0u;
        return;
    }
    const size_t n4 = (size_t)HN * HN / 4;
    const size_t stride = (size_t)(gridDim.x - 1) * 256;
    for (size_t i = (size_t)blockIdx.x * 256 + threadIdx.x; i < n4; i += stride) {
        float4 a = r4[i], b = m4[i], c = b4[i];
        float4 o;
        o.x = a.x * b.x * c.x;
        o.y = a.y * b.y * c.y;
        o.z = a.z * b.z * c.z;
        o.w = a.w * b.w * c.w;
        e4[i] = o;
    }
}

// ---------------- K2: w_outT[h][o] = w_out[o][h] ----------------------------
__global__ __launch_bounds__(256) void k_transpose(const float* __restrict__ wout,
                                                   float* __restrict__ wT)
{
    __shared__ float tile[64][65];
    const int h0 = blockIdx.x * 64;
    const int o0 = blockIdx.y * 64;
    const int lx = threadIdx.x & 63, ly = threadIdx.x >> 6;  // ly 0..3
    #pragma unroll
    for (int i = 0; i < 16; ++i) {
        int o = ly + 4 * i;
        tile[o][lx] = wout[(size_t)(o0 + o) * HN + h0 + lx];
    }
    __syncthreads();
    #pragma unroll
    for (int i = 0; i < 16; ++i) {
        int h = ly + 4 * i;
        wT[(size_t)(h0 + h) * NOUTC + o0 + lx] = tile[lx][h];
    }
}

// ---------------- K3: ff[t][h] = sum_i x[t][i]*w_fc1[h][i]  (fp64 acc) ------
__global__ __launch_bounds__(256) void k_ff(const float* __restrict__ x,
                                            const float* __restrict__ w,
                                            double* __restrict__ ff)
{
    __shared__ float xs[16][36];
    __shared__ float wsT[32][129];
    const int h0 = blockIdx.x * 128;
    const int t0 = blockIdx.y * 16;
    const int tid = threadIdx.x;
    const int tq = tid >> 5, hq = tid & 31;
    double acc[2][4] = {};
    for (int kc = 0; kc < NIN; kc += 32) {
        __syncthreads();
        #pragma unroll
        for (int s2 = 0; s2 < 2; ++s2) {
            int e = tid + s2 * 256; int t = e >> 5, k = e & 31;
            xs[t][k] = x[(size_t)(t0 + t) * NIN + kc + k];
        }
        #pragma unroll
        for (int s2 = 0; s2 < 16; ++s2) {
            int e = tid + s2 * 256; int h = e >> 5, k = e & 31;
            wsT[k][h] = w[(size_t)(h0 + h) * NIN + kc + k];
        }
        __syncthreads();
        #pragma unroll 8
        for (int k = 0; k < 32; ++k) {
            double a0 = (double)xs[tq][k];
            double a1 = (double)xs[tq + 8][k];
            double b0 = (double)wsT[k][hq];
            double b1 = (double)wsT[k][hq + 32];
            double b2 = (double)wsT[k][hq + 64];
            double b3 = (double)wsT[k][hq + 96];
            acc[0][0] += a0 * b0; acc[0][1] += a0 * b1; acc[0][2] += a0 * b2; acc[0][3] += a0 * b3;
            acc[1][0] += a1 * b0; acc[1][1] += a1 * b1; acc[1][2] += a1 * b2; acc[1][3] += a1 * b3;
        }
    }
    #pragma unroll
    for (int i = 0; i < 2; ++i)
        #pragma unroll
        for (int j = 0; j < 4; ++j)
            ff[(size_t)(t0 + tq + 8 * i) * HN + h0 + hq + 32 * j] = acc[i][j];
}

// ---------------- K4: persistent scan over T=128 steps ----------------------
__global__ __launch_bounds__(1024) void k_loop(
    const float* __restrict__ eff, const float* __restrict__ wT,
    const double* __restrict__ ff, const float* __restrict__ tau,
    unsigned long long* spk, unsigned* AwP, unsigned* N0wP, unsigned* N1wP,
    unsigned* Nacc, unsigned* bar, float* out)
{
    __shared__ unsigned long long s_words[64];
    __shared__ unsigned short s_list[2048];
    __shared__ int s_cnt[64];
    __shared__ int s_k;
    __shared__ double s_part[16][64];

    const int wg = blockIdx.x;
    const int tid = threadIdx.x;
    const int wv = tid >> 6;
    const int lane = tid & 63;
    const bool isH = (wg < NWGH);

    const int c0 = wg * 64;
    const int o0 = (wg - NWGH) * 64;
    const size_t rstride = isH ? (size_t)HN : (size_t)NOUTC;
    const float* gbase = isH ? (eff + c0 + lane) : (wT + o0 + lane);

    // ---- prologue: WG-local deterministic column totals (subtract mode) ----
    {
        const float* pc = gbase + (size_t)(wv * 256) * rstride;
        double s = 0.0;
        #pragma unroll 4
        for (int r = 0; r < 256; ++r) s += (double)pc[(size_t)r * rstride];
        s_part[wv][lane] = s;
    }
    __syncthreads();

    double colv = 0.0;
    float  tauv = 0.f;
    double hm = 0.0, om = 0.0;
    int sp1 = 0, sp2 = 0, osp = 0;
    unsigned curA = 0, curN0 = 0, curN1 = 0, naccr = 0;
    if (wv == 0) {
        #pragma unroll
        for (int p2 = 0; p2 < 16; ++p2) colv += s_part[p2][lane];
        if (isH) tauv = tau[c0 + lane];
    }
    unsigned lsense = 0;

    for (int it = 0; it <= TT; ++it) {
        const bool active = isH ? (it < TT) : (it > 0);
        if (active) {
            unsigned long long* rb = spk + (size_t)((it + 1) & 1) * 64;
            if (tid < 64)
                s_words[tid] = __hip_atomic_load(&rb[tid], __ATOMIC_ACQUIRE, __HIP_MEMORY_SCOPE_AGENT);
            __syncthreads();
            if (tid == 0) {
                int k = 0;
                #pragma unroll
                for (int i2 = 0; i2 < 64; ++i2) k += __popcll(s_words[i2]);
                s_k = k;
            }
            __syncthreads();
            const int k = s_k;
            const bool gspk = (k <= HN / 2);
            const int nlist = gspk ? k : HN - k;
            unsigned long long myw = 0;
            if (tid < 64) {
                myw = gspk ? s_words[tid] : ~s_words[tid];
                s_cnt[tid] = __popcll(myw);
            }
            __syncthreads();
            if (tid == 0) {
                int a = 0;
                #pragma unroll
                for (int i2 = 0; i2 < 64; ++i2) { int c = s_cnt[i2]; s_cnt[i2] = a; a += c; }
            }
            __syncthreads();
            if (tid < 64) {
                int b = s_cnt[tid];
                unsigned long long w2 = myw;
                while (w2) {
                    int bpos = __builtin_ctzll(w2);
                    s_list[b++] = (unsigned short)(tid * 64 + bpos);
                    w2 &= w2 - 1;
                }
            }
            __syncthreads();
            // ---- gather rows: wave wv handles list slots ≡ wv (mod 16) ----
            double acc = 0.0;
            int idx = wv;
            for (; idx + 48 < nlist; idx += 64) {
                int r0 = s_list[idx];
                int r1 = s_list[idx + 16];
                int r2 = s_list[idx + 32];
                int r3 = s_list[idx + 48];
                float v0 = gbase[(size_t)r0 * rstride];
                float v1 = gbase[(size_t)r1 * rstride];
                float v2 = gbase[(size_t)r2 * rstride];
                float v3 = gbase[(size_t)r3 * rstride];
                acc += ((double)v0 + (double)v1) + ((double)v2 + (double)v3);
            }
            for (; idx < nlist; idx += 16)
                acc += (double)gbase[(size_t)s_list[idx] * rstride];
            s_part[wv][lane] = acc;
            __syncthreads();

            if (wv == 0) {
                double ssum = 0.0;
                #pragma unroll
                for (int p2 = 0; p2 < 16; ++p2) ssum += s_part[p2][lane];
                double drive = gspk ? ssum : (colv - ssum);
                if (isH) {
                    const int t = it;
                    double cur = ff[(size_t)t * HN + c0 + lane] + 0.1 * drive;
                    hm = hm * (double)tauv * (double)(1 - sp1) + cur;
                    int s = (hm >= 0.5) ? 1 : 0;
                    int n = s + sp1 + sp2;        // window count after append
                    sp2 = sp1; sp1 = s;
                    naccr += (unsigned)n;
                    unsigned bit = 1u << (t & 31);
                    if (s)     curA  |= bit;
                    if (n & 1) curN0 |= bit;
                    if (n & 2) curN1 |= bit;
                    if ((t & 31) == 31) {
                        const int wq = t >> 5;
                        AwP [wq * HN + c0 + lane] = curA;
                        N0wP[wq * HN + c0 + lane] = curN0;
                        N1wP[wq * HN + c0 + lane] = curN1;
                        curA = curN0 = curN1 = 0u;
                    }
                    unsigned long long ball = __ballot(s != 0);
                    if (lane == 0)
                        __hip_atomic_store(&spk[(size_t)(t & 1) * 64 + wg], ball,
                                           __ATOMIC_RELEASE, __HIP_MEMORY_SCOPE_AGENT);
                    if (t == TT - 1) Nacc[c0 + lane] = naccr;
                } else {
                    const int t = it - 1;
                    om = om * 0.96 * (double)(1 - osp) + drive;
                    osp = (om >= 0.5) ? 1 : 0;
                    out[(size_t)t * NOUTC + o0 + lane] = osp ? 1.0f : 0.0f;
                }
            }
        }
        if (it < TT) gridbar(bar, NWGT, lsense);
    }
}

// ---------------- K5: rec_out = recurrent + 0.01*(3T - 2N[i] + 2M[i][j]) ----
__global__ __launch_bounds__(256) void k_rec(const float* __restrict__ recur,
    const unsigned* __restrict__ AwP, const unsigned* __restrict__ N0wP,
    const unsigned* __restrict__ N1wP, const unsigned* __restrict__ Nacc,
    float* __restrict__ out)
{
    const int j = blockIdx.x * 256 + threadIdx.x;
    const int i0 = blockIdx.y * 32;
    const unsigned a0 = AwP[0 * HN + j], a1 = AwP[1 * HN + j];
    const unsigned a2 = AwP[2 * HN + j], a3 = AwP[3 * HN + j];
    for (int ii = 0; ii < 32; ++ii) {
        const int i = i0 + ii;
        const unsigned n00 = N0wP[0 * HN + i], n01 = N0wP[1 * HN + i];
        const unsigned n02 = N0wP[2 * HN + i], n03 = N0wP[3 * HN + i];
        const unsigned n10 = N1wP[0 * HN + i], n11 = N1wP[1 * HN + i];
        const unsigned n12 = N1wP[2 * HN + i], n13 = N1wP[3 * HN + i];
        int M = __popc(a0 & n00) + __popc(a1 & n01) + __popc(a2 & n02) + __popc(a3 & n03);
        M += 2 * (__popc(a0 & n10) + __popc(a1 & n11) + __popc(a2 & n12) + __popc(a3 & n13));
        const int D = 3 * TT - 2 * (int)Nacc[i] + 2 * M;
        out[(size_t)i * HN + j] = (float)((double)recur[(size_t)i * HN + j] + 0.01 * (double)D);
    }
}

// ---------------- host ------------------------------------------------------
extern "C" void kernel_launch(void* const* d_in, const int* in_sizes, int n_in,
                              void* d_out, int out_size, void* d_ws, size_t ws_size,
                              hipStream_t stream) {
    const float* x         = (const float*)d_in[0];
    const float* w_fc1     = (const float*)d_in[1];
    const float* w_out     = (const float*)d_in[2];
    const float* recurrent = (const float*)d_in[3];
    const float* tau       = (const float*)d_in[4];
    const float* mask      = (const float*)d_in[5];
    const float* binary    = (const float*)d_in[6];
    float* out = (float*)d_out;
    float* rec_out = out + (size_t)TT * NOUTC;   // [HN,HN] region of d_out
    float* eff = rec_out;                         // reused as eff_rec scratch

    char* ws = (char*)d_ws;
    size_t off = 0;
    float* wT  = (float*)(ws + off);                 off += (size_t)HN * NOUTC * 4;   // 4MB
    double* ff = (double*)(ws + off);                off += (size_t)TT * HN * 8;      // 4MB
    // zero-span (contiguous): spk, bar
    unsigned long long* spk = (unsigned long long*)(ws + off); off += 2 * 64 * 8;     // 1KB
    unsigned* bar = (unsigned*)(ws + off);           off += 256;
    const int zwords = (int)((2 * 64 * 8 + 256) / 4);
    unsigned* AwP  = (unsigned*)(ws + off);          off += (size_t)4 * HN * 4;       // 64KB
    unsigned* N0wP = (unsigned*)(ws + off);          off += (size_t)4 * HN * 4;
    unsigned* N1wP = (unsigned*)(ws + off);          off += (size_t)4 * HN * 4;
    unsigned* Nacc = (unsigned*)(ws + off);          off += (size_t)HN * 4;

    if (ws_size < off) return;  // refuse to corrupt memory if scratch too small

    k_eff_zero<<<dim3(2049), dim3(256), 0, stream>>>(
        (const float4*)recurrent, (const float4*)mask, (const float4*)binary,
        (float4*)eff, (unsigned*)spk, zwords);
    k_transpose<<<dim3(64, 4), dim3(256), 0, stream>>>(w_out, wT);
    k_ff<<<dim3(32, 8), dim3(256), 0, stream>>>(x, w_fc1, ff);
    k_loop<<<dim3(NWGT), dim3(1024), 0, stream>>>(eff, wT, ff, tau,
                                                  spk, AwP, N0wP, N1wP, Nacc, bar, out);
    k_rec<<<dim3(16, 128), dim3(256), 0, stream>>>(recurrent, AwP, N0wP, N1wP, Nacc,
                                                   rec_out);
}

// Round 4
// 973.384 us; speedup vs baseline: 1.5049x; 1.5049x over previous
//
#include <hip/hip_runtime.h>
#include <cstdint>
#include <cstddef>

#define HN    4096
#define TT    128
#define NIN   1024
#define NOUTC 256
#define NWGH  32            // hidden WGs, 128 columns each
#define NWGO  2             // output WGs, 128 columns each
#define NWGT  (NWGH + NWGO)

// ---------------- device-wide sense-reversing barrier (bounded spin) --------
__device__ __forceinline__ void gridbar(unsigned* bar, unsigned nwg, unsigned& lsense) {
    __syncthreads();
    if (threadIdx.x == 0) {
        unsigned s = lsense ^ 1u;
        lsense = s;
        unsigned prev = __hip_atomic_fetch_add(&bar[0], 1u, __ATOMIC_ACQ_REL, __HIP_MEMORY_SCOPE_AGENT);
        if (prev == nwg - 1u) {
            __hip_atomic_store(&bar[0], 0u, __ATOMIC_RELAXED, __HIP_MEMORY_SCOPE_AGENT);
            __hip_atomic_store(&bar[1], s, __ATOMIC_RELEASE, __HIP_MEMORY_SCOPE_AGENT);
        } else {
            int budget = 1 << 18;   // bounded: never hang the GPU
            while (__hip_atomic_load(&bar[1], __ATOMIC_ACQUIRE, __HIP_MEMORY_SCOPE_AGENT) != s) {
                __builtin_amdgcn_s_sleep(1);
                if (--budget == 0) break;
            }
        }
    }
    __syncthreads();
}

// -------- K1: eff = recurrent*mask*binary (into d_out rec region) + zero sync span
__global__ __launch_bounds__(256) void k_eff_zero(
    const float4* __restrict__ r4, const float4* __restrict__ m4,
    const float4* __restrict__ b4, float4* __restrict__ e4,
    unsigned* __restrict__ zbase, int zwords)
{
    if (blockIdx.x == gridDim.x - 1) {
        for (int i = threadIdx.x; i < zwords; i += 256) zbase[i] = 0u;
        return;
    }
    const size_t n4 = (size_t)HN * HN / 4;
    const size_t stride = (size_t)(gridDim.x - 1) * 256;
    for (size_t i = (size_t)blockIdx.x * 256 + threadIdx.x; i < n4; i += stride) {
        float4 a = r4[i], b = m4[i], c = b4[i];
        float4 o;
        o.x = a.x * b.x * c.x;
        o.y = a.y * b.y * c.y;
        o.z = a.z * b.z * c.z;
        o.w = a.w * b.w * c.w;
        e4[i] = o;
    }
}

// ---------------- K2: w_outT[h][o] = w_out[o][h] ----------------------------
__global__ __launch_bounds__(256) void k_transpose(const float* __restrict__ wout,
                                                   float* __restrict__ wT)
{
    __shared__ float tile[64][65];
    const int h0 = blockIdx.x * 64;
    const int o0 = blockIdx.y * 64;
    const int lx = threadIdx.x & 63, ly = threadIdx.x >> 6;  // ly 0..3
    #pragma unroll
    for (int i = 0; i < 16; ++i) {
        int o = ly + 4 * i;
        tile[o][lx] = wout[(size_t)(o0 + o) * HN + h0 + lx];
    }
    __syncthreads();
    #pragma unroll
    for (int i = 0; i < 16; ++i) {
        int h = ly + 4 * i;
        wT[(size_t)(h0 + h) * NOUTC + o0 + lx] = tile[lx][h];
    }
}

// ---------------- K3: ff[t][h] = sum_i x[t][i]*w_fc1[h][i]  (fp64 acc) ------
__global__ __launch_bounds__(256) void k_ff(const float* __restrict__ x,
                                            const float* __restrict__ w,
                                            double* __restrict__ ff)
{
    __shared__ float xs[16][36];
    __shared__ float wsT[32][129];
    const int h0 = blockIdx.x * 128;
    const int t0 = blockIdx.y * 16;
    const int tid = threadIdx.x;
    const int tq = tid >> 5, hq = tid & 31;
    double acc[2][4] = {};
    for (int kc = 0; kc < NIN; kc += 32) {
        __syncthreads();
        #pragma unroll
        for (int s2 = 0; s2 < 2; ++s2) {
            int e = tid + s2 * 256; int t = e >> 5, k = e & 31;
            xs[t][k] = x[(size_t)(t0 + t) * NIN + kc + k];
        }
        #pragma unroll
        for (int s2 = 0; s2 < 16; ++s2) {
            int e = tid + s2 * 256; int h = e >> 5, k = e & 31;
            wsT[k][h] = w[(size_t)(h0 + h) * NIN + kc + k];
        }
        __syncthreads();
        #pragma unroll 8
        for (int k = 0; k < 32; ++k) {
            double a0 = (double)xs[tq][k];
            double a1 = (double)xs[tq + 8][k];
            double b0 = (double)wsT[k][hq];
            double b1 = (double)wsT[k][hq + 32];
            double b2 = (double)wsT[k][hq + 64];
            double b3 = (double)wsT[k][hq + 96];
            acc[0][0] += a0 * b0; acc[0][1] += a0 * b1; acc[0][2] += a0 * b2; acc[0][3] += a0 * b3;
            acc[1][0] += a1 * b0; acc[1][1] += a1 * b1; acc[1][2] += a1 * b2; acc[1][3] += a1 * b3;
        }
    }
    #pragma unroll
    for (int i = 0; i < 2; ++i)
        #pragma unroll
        for (int j = 0; j < 4; ++j)
            ff[(size_t)(t0 + tq + 8 * i) * HN + h0 + hq + 32 * j] = acc[i][j];
}

// ---------------- K4: persistent scan over T=128 steps ----------------------
// 34 WGs x 1024 threads. Hidden WG wg<32 owns cols [wg*128, wg*128+128);
// waves 0,1 are "update waves" (wave wv owns cols wg*128+wv*64+lane and
// publishes ballot word wg*2+wv). All 16 waves gather.
__global__ __launch_bounds__(1024) void k_loop(
    const float* __restrict__ eff, const float* __restrict__ wT,
    const double* __restrict__ ff, const float* __restrict__ tau,
    unsigned long long* spk, unsigned* AwP, unsigned* N0wP, unsigned* N1wP,
    unsigned* Nacc, unsigned* bar, float* out)
{
    __shared__ unsigned short s_list[2048];
    __shared__ double s_part[16][128];
    __shared__ int s_k, s_gspk;

    const int wg = blockIdx.x;
    const int tid = threadIdx.x;
    const int wv = tid >> 6;
    const int lane = tid & 63;
    const bool isH = (wg < NWGH);

    const size_t rstride = isH ? (size_t)HN : (size_t)NOUTC;
    const int base0 = isH ? wg * 128 : (wg - NWGH) * 128;
    const float* gbase = (isH ? eff : wT) + base0 + lane;
    const int c = base0 + wv * 64 + lane;   // column for update waves (wv<2)

    // ---- prologue: WG-local deterministic column totals (subtract mode) ----
    {
        const float* p0 = gbase + (size_t)(wv * 256) * rstride;
        double s0 = 0.0, s1 = 0.0;
        #pragma unroll 4
        for (int r = 0; r < 256; ++r) {
            s0 += (double)p0[(size_t)r * rstride];
            s1 += (double)p0[(size_t)r * rstride + 64];
        }
        s_part[wv][lane] = s0;
        s_part[wv][64 + lane] = s1;
    }
    __syncthreads();

    double colv = 0.0;
    float  tauv = 0.f;
    if (wv < 2) {
        #pragma unroll
        for (int p = 0; p < 16; ++p) colv += s_part[p][wv * 64 + lane];
        if (isH) tauv = tau[c];
    }

    double hm = 0.0, om = 0.0;
    int sp1 = 0, sp2 = 0, osp = 0;
    unsigned curA = 0, curN0 = 0, curN1 = 0, naccr = 0;
    unsigned lsense = 0;

    for (int it = 0; it <= TT; ++it) {
        const bool active = isH ? (it < TT) : (it > 0);
        if (active) {
            // prefetch ff early; latency hides under the ballot scan
            double ffv = 0.0;
            if (isH && wv < 2) ffv = ff[(size_t)it * HN + c];

            // ---- wave 0: fully parallel ballot scan + list build ----------
            if (tid < 64) {
                unsigned long long w = __hip_atomic_load(
                    &spk[(size_t)((it + 1) & 1) * 64 + lane],
                    __ATOMIC_ACQUIRE, __HIP_MEMORY_SCOPE_AGENT);
                int pc = __popcll(w);
                int k = pc;
                #pragma unroll
                for (int d = 1; d < 64; d <<= 1) k += __shfl_xor(k, d, 64);
                const bool gspk = (k <= HN / 2);
                unsigned long long myw = gspk ? w : ~w;
                int cnt = __popcll(myw);
                int incl = cnt;
                #pragma unroll
                for (int d = 1; d < 64; d <<= 1) {
                    int o = __shfl_up(incl, d, 64);
                    if (lane >= d) incl += o;
                }
                int b = incl - cnt;
                while (myw) {
                    int bp = __builtin_ctzll(myw);
                    s_list[b++] = (unsigned short)(lane * 64 + bp);
                    myw &= myw - 1;
                }
                if (lane == 63) { s_k = incl; s_gspk = gspk ? 1 : 0; }
            }
            __syncthreads();

            // ---- gather (all 16 waves, 2 columns per lane) ----------------
            const int nlist = s_k;
            double acc0 = 0.0, acc1 = 0.0;
            for (int idx = wv; idx < nlist; idx += 16) {
                const float* rp = gbase + (size_t)s_list[idx] * rstride;
                acc0 += (double)rp[0];
                acc1 += (double)rp[64];
            }
            s_part[wv][lane] = acc0;
            s_part[wv][64 + lane] = acc1;
            __syncthreads();

            // ---- update waves ---------------------------------------------
            if (wv < 2) {
                double ssum = 0.0;
                #pragma unroll
                for (int p = 0; p < 16; ++p) ssum += s_part[p][wv * 64 + lane];
                double drive = s_gspk ? ssum : (colv - ssum);
                if (isH) {
                    const int t = it;
                    double cur = ffv + 0.1 * drive;
                    hm = hm * (double)tauv * (double)(1 - sp1) + cur;
                    int s = (hm >= 0.5) ? 1 : 0;
                    int n = s + sp1 + sp2;       // STDP window count after append
                    sp2 = sp1; sp1 = s;
                    naccr += (unsigned)n;
                    unsigned bit = 1u << (t & 31);
                    if (s)     curA  |= bit;
                    if (n & 1) curN0 |= bit;
                    if (n & 2) curN1 |= bit;
                    if ((t & 31) == 31) {
                        const int wq = t >> 5;
                        AwP [wq * HN + c] = curA;
                        N0wP[wq * HN + c] = curN0;
                        N1wP[wq * HN + c] = curN1;
                        curA = curN0 = curN1 = 0u;
                    }
                    unsigned long long ball = __ballot(s != 0);
                    if (lane == 0)
                        __hip_atomic_store(&spk[(size_t)(t & 1) * 64 + wg * 2 + wv], ball,
                                           __ATOMIC_RELEASE, __HIP_MEMORY_SCOPE_AGENT);
                    if (t == TT - 1) Nacc[c] = naccr;
                    __threadfence();   // drain this wave's spike-word store before barrier
                } else {
                    const int t = it - 1;
                    om = om * 0.96 * (double)(1 - osp) + drive;
                    osp = (om >= 0.5) ? 1 : 0;
                    out[(size_t)t * NOUTC + c] = osp ? 1.0f : 0.0f;
                }
            }
        }
        if (it < TT) gridbar(bar, NWGT, lsense);
    }
}

// ---------------- K5: rec_out = recurrent + 0.01*(3T - 2N[i] + 2M[i][j]) ----
__global__ __launch_bounds__(256) void k_rec(const float* __restrict__ recur,
    const unsigned* __restrict__ AwP, const unsigned* __restrict__ N0wP,
    const unsigned* __restrict__ N1wP, const unsigned* __restrict__ Nacc,
    float* __restrict__ out)
{
    const int j = blockIdx.x * 256 + threadIdx.x;
    const int i0 = blockIdx.y * 32;
    const unsigned a0 = AwP[0 * HN + j], a1 = AwP[1 * HN + j];
    const unsigned a2 = AwP[2 * HN + j], a3 = AwP[3 * HN + j];
    for (int ii = 0; ii < 32; ++ii) {
        const int i = i0 + ii;
        const unsigned n00 = N0wP[0 * HN + i], n01 = N0wP[1 * HN + i];
        const unsigned n02 = N0wP[2 * HN + i], n03 = N0wP[3 * HN + i];
        const unsigned n10 = N1wP[0 * HN + i], n11 = N1wP[1 * HN + i];
        const unsigned n12 = N1wP[2 * HN + i], n13 = N1wP[3 * HN + i];
        int M = __popc(a0 & n00) + __popc(a1 & n01) + __popc(a2 & n02) + __popc(a3 & n03);
        M += 2 * (__popc(a0 & n10) + __popc(a1 & n11) + __popc(a2 & n12) + __popc(a3 & n13));
        const int D = 3 * TT - 2 * (int)Nacc[i] + 2 * M;
        out[(size_t)i * HN + j] = (float)((double)recur[(size_t)i * HN + j] + 0.01 * (double)D);
    }
}

// ---------------- host ------------------------------------------------------
extern "C" void kernel_launch(void* const* d_in, const int* in_sizes, int n_in,
                              void* d_out, int out_size, void* d_ws, size_t ws_size,
                              hipStream_t stream) {
    const float* x         = (const float*)d_in[0];
    const float* w_fc1     = (const float*)d_in[1];
    const float* w_out     = (const float*)d_in[2];
    const float* recurrent = (const float*)d_in[3];
    const float* tau       = (const float*)d_in[4];
    const float* mask      = (const float*)d_in[5];
    const float* binary    = (const float*)d_in[6];
    float* out = (float*)d_out;
    float* rec_out = out + (size_t)TT * NOUTC;   // [HN,HN] region of d_out
    float* eff = rec_out;                         // reused as eff_rec scratch

    char* ws = (char*)d_ws;
    size_t off = 0;
    float* wT  = (float*)(ws + off);                 off += (size_t)HN * NOUTC * 4;   // 4MB
    double* ff = (double*)(ws + off);                off += (size_t)TT * HN * 8;      // 4MB
    // zero-span (contiguous): spk, bar
    unsigned long long* spk = (unsigned long long*)(ws + off); off += 2 * 64 * 8;     // 1KB
    unsigned* bar = (unsigned*)(ws + off);           off += 256;
    const int zwords = (int)((2 * 64 * 8 + 256) / 4);
    unsigned* AwP  = (unsigned*)(ws + off);          off += (size_t)4 * HN * 4;       // 64KB
    unsigned* N0wP = (unsigned*)(ws + off);          off += (size_t)4 * HN * 4;
    unsigned* N1wP = (unsigned*)(ws + off);          off += (size_t)4 * HN * 4;
    unsigned* Nacc = (unsigned*)(ws + off);          off += (size_t)HN * 4;

    if (ws_size < off) return;  // refuse to corrupt memory if scratch too small

    k_eff_zero<<<dim3(2049), dim3(256), 0, stream>>>(
        (const float4*)recurrent, (const float4*)mask, (const float4*)binary,
        (float4*)eff, (unsigned*)spk, zwords);
    k_transpose<<<dim3(64, 4), dim3(256), 0, stream>>>(w_out, wT);
    k_ff<<<dim3(32, 8), dim3(256), 0, stream>>>(x, w_fc1, ff);
    k_loop<<<dim3(NWGT), dim3(1024), 0, stream>>>(eff, wT, ff, tau,
                                                  spk, AwP, N0wP, N1wP, Nacc, bar, out);
    k_rec<<<dim3(16, 128), dim3(256), 0, stream>>>(recurrent, AwP, N0wP, N1wP, Nacc,
                                                   rec_out);
}

// Round 5
// 823.741 us; speedup vs baseline: 1.7783x; 1.1817x over previous
//
#include <hip/hip_runtime.h>
#include <cstdint>
#include <cstddef>

#define HN    4096
#define TT    128
#define NIN   1024
#define NOUTC 256
#define NWGH  16            // hidden WGs, 256 columns each (4 update waves)
#define NWGO  1             // output WG, 256 columns
#define NWGT  (NWGH + NWGO)
#define NCOLS (HN + NOUTC)  // colsum table width
#define NRB   16            // row-blocks in k_colsum

// -------- K1: eff = recurrent*mask*binary (into d_out rec region) + zero sync span
__global__ __launch_bounds__(256) void k_eff_zero(
    const float4* __restrict__ r4, const float4* __restrict__ m4,
    const float4* __restrict__ b4, float4* __restrict__ e4,
    unsigned* __restrict__ zbase, int zwords)
{
    if (blockIdx.x == gridDim.x - 1) {
        for (int i = threadIdx.x; i < zwords; i += 256) zbase[i] = 0u;
        return;
    }
    const size_t n4 = (size_t)HN * HN / 4;
    const size_t stride = (size_t)(gridDim.x - 1) * 256;
    for (size_t i = (size_t)blockIdx.x * 256 + threadIdx.x; i < n4; i += stride) {
        float4 a = r4[i], b = m4[i], c = b4[i];
        float4 o;
        o.x = a.x * b.x * c.x;
        o.y = a.y * b.y * c.y;
        o.z = a.z * b.z * c.z;
        o.w = a.w * b.w * c.w;
        e4[i] = o;
    }
}

// ---------------- K2: w_outT[h][o] = w_out[o][h] ----------------------------
__global__ __launch_bounds__(256) void k_transpose(const float* __restrict__ wout,
                                                   float* __restrict__ wT)
{
    __shared__ float tile[64][65];
    const int h0 = blockIdx.x * 64;
    const int o0 = blockIdx.y * 64;
    const int lx = threadIdx.x & 63, ly = threadIdx.x >> 6;  // ly 0..3
    #pragma unroll
    for (int i = 0; i < 16; ++i) {
        int o = ly + 4 * i;
        tile[o][lx] = wout[(size_t)(o0 + o) * HN + h0 + lx];
    }
    __syncthreads();
    #pragma unroll
    for (int i = 0; i < 16; ++i) {
        int h = ly + 4 * i;
        wT[(size_t)(h0 + h) * NOUTC + o0 + lx] = tile[lx][h];
    }
}

// ---------------- K3: ff[t][h] = sum_i x[t][i]*w_fc1[h][i]  (fp64 acc) ------
__global__ __launch_bounds__(256) void k_ff(const float* __restrict__ x,
                                            const float* __restrict__ w,
                                            double* __restrict__ ff)
{
    __shared__ float xs[16][36];
    __shared__ float wsT[32][129];
    const int h0 = blockIdx.x * 128;
    const int t0 = blockIdx.y * 16;
    const int tid = threadIdx.x;
    const int tq = tid >> 5, hq = tid & 31;
    double acc[2][4] = {};
    for (int kc = 0; kc < NIN; kc += 32) {
        __syncthreads();
        #pragma unroll
        for (int s2 = 0; s2 < 2; ++s2) {
            int e = tid + s2 * 256; int t = e >> 5, k = e & 31;
            xs[t][k] = x[(size_t)(t0 + t) * NIN + kc + k];
        }
        #pragma unroll
        for (int s2 = 0; s2 < 16; ++s2) {
            int e = tid + s2 * 256; int h = e >> 5, k = e & 31;
            wsT[k][h] = w[(size_t)(h0 + h) * NIN + kc + k];
        }
        __syncthreads();
        #pragma unroll 8
        for (int k = 0; k < 32; ++k) {
            double a0 = (double)xs[tq][k];
            double a1 = (double)xs[tq + 8][k];
            double b0 = (double)wsT[k][hq];
            double b1 = (double)wsT[k][hq + 32];
            double b2 = (double)wsT[k][hq + 64];
            double b3 = (double)wsT[k][hq + 96];
            acc[0][0] += a0 * b0; acc[0][1] += a0 * b1; acc[0][2] += a0 * b2; acc[0][3] += a0 * b3;
            acc[1][0] += a1 * b0; acc[1][1] += a1 * b1; acc[1][2] += a1 * b2; acc[1][3] += a1 * b3;
        }
    }
    #pragma unroll
    for (int i = 0; i < 2; ++i)
        #pragma unroll
        for (int j = 0; j < 4; ++j)
            ff[(size_t)(t0 + tq + 8 * i) * HN + h0 + hq + 32 * j] = acc[i][j];
}

// ---------------- K3b: deterministic column partial sums --------------------
// grid (17, NRB): bx<16 -> eff cols [bx*256,+256); bx==16 -> wT cols 0..255.
// Each block sums 256 rows; colP[rb][NCOLS] partials, reduced in k_loop prologue.
__global__ __launch_bounds__(256) void k_colsum(const float* __restrict__ eff,
                                                const float* __restrict__ wT,
                                                double* __restrict__ colP)
{
    const int bx = blockIdx.x, by = blockIdx.y, t = threadIdx.x;
    double s = 0.0;
    if (bx < 16) {
        const float* p = eff + (size_t)by * 256 * HN + bx * 256 + t;
        #pragma unroll 8
        for (int r = 0; r < 256; ++r) s += (double)p[(size_t)r * HN];
        colP[(size_t)by * NCOLS + bx * 256 + t] = s;
    } else {
        const float* p = wT + (size_t)by * 256 * NOUTC + t;
        #pragma unroll 8
        for (int r = 0; r < 256; ++r) s += (double)p[(size_t)r * NOUTC];
        colP[(size_t)by * NCOLS + HN + t] = s;
    }
}

// ---------------- K4: persistent scan over T=128 steps ----------------------
// 17 WGs x 1024 threads. Hidden WG wg<16 owns cols [wg*256,+256); waves 0..3
// are update waves (wave wv owns cols wg*256+wv*64+lane, ballot word wg*4+wv).
// Global spike count k is carried IN the barrier release word: steady-state
// steps (nlist==0) skip spike loads, gather, and both inner syncthreads.
__global__ __launch_bounds__(1024) void k_loop(
    const float* __restrict__ eff, const float* __restrict__ wT,
    const double* __restrict__ ff, const float* __restrict__ tau,
    const double* __restrict__ colP,
    unsigned long long* spk, unsigned* AwP, unsigned* N0wP, unsigned* N1wP,
    unsigned* Nacc, unsigned long long* bar, float* out)
{
    __shared__ unsigned short s_list[2048];
    __shared__ double s_part[16][256];
    __shared__ int s_wcnt[4];
    __shared__ int s_kbc;

    const int wg = blockIdx.x;
    const int tid = threadIdx.x;
    const int wv = tid >> 6;
    const int lane = tid & 63;
    const bool isH = (wg < NWGH);

    const size_t rstride = isH ? (size_t)HN : (size_t)NOUTC;
    const int base0 = isH ? wg * 256 : 0;
    const float* gbase = (isH ? eff : wT) + base0 + lane;
    const int c = base0 + wv * 64 + lane;   // update-wave column (wv<4)

    // ---- prologue: reduce precomputed column partials (deterministic) ------
    double colv = 0.0, hm = 0.0, om = 0.0, ffv = 0.0;
    float tauv = 0.f;
    int sp1 = 0, sp2 = 0, osp = 0;
    unsigned curA = 0, curN0 = 0, curN1 = 0, naccr = 0;
    if (wv < 4) {
        const int ci = isH ? c : (HN + c);
        #pragma unroll
        for (int rb = 0; rb < NRB; ++rb) colv += colP[(size_t)rb * NCOLS + ci];
        if (isH) { tauv = tau[c]; ffv = ff[c]; }   // ff row 0 prefetch
    }
    unsigned lsense = 0;
    int kcur = 0;                                   // k=0 before step 0

    for (int it = 0; it <= TT; ++it) {
        const bool active = isH ? (it < TT) : (it > 0);
        if (active) {
            const int k = kcur;
            const bool gspk = (k <= HN / 2);
            const int nlist = gspk ? k : HN - k;
            if (nlist > 0) {
                // ---- transient path: build spiking(/silent) row list ------
                if (tid < 64) {
                    unsigned long long w = __hip_atomic_load(
                        &spk[(size_t)((it + 1) & 1) * 64 + lane],
                        __ATOMIC_RELAXED, __HIP_MEMORY_SCOPE_AGENT);
                    unsigned long long myw = gspk ? w : ~w;
                    int cnt = __popcll(myw);
                    int incl = cnt;
                    #pragma unroll
                    for (int d = 1; d < 64; d <<= 1) {
                        int o = __shfl_up(incl, d, 64);
                        if (lane >= d) incl += o;
                    }
                    int b = incl - cnt;
                    while (myw) {
                        int bp = __builtin_ctzll(myw);
                        s_list[b++] = (unsigned short)(lane * 64 + bp);
                        myw &= myw - 1;
                    }
                }
                __syncthreads();
                double a0 = 0.0, a1 = 0.0, a2 = 0.0, a3 = 0.0;
                for (int idx = wv; idx < nlist; idx += 16) {
                    const float* rp = gbase + (size_t)s_list[idx] * rstride;
                    a0 += (double)rp[0];
                    a1 += (double)rp[64];
                    a2 += (double)rp[128];
                    a3 += (double)rp[192];
                }
                s_part[wv][lane] = a0;
                s_part[wv][64 + lane] = a1;
                s_part[wv][128 + lane] = a2;
                s_part[wv][192 + lane] = a3;
                __syncthreads();
            }
            if (wv < 4) {
                double ssum = 0.0;
                if (nlist > 0) {
                    const int j = wv * 64 + lane;
                    #pragma unroll
                    for (int p = 0; p < 16; ++p) ssum += s_part[p][j];
                }
                double drive = gspk ? ssum : (colv - ssum);
                if (isH) {
                    const int t = it;
                    double cur = ffv + 0.1 * drive;
                    hm = hm * (double)tauv * (double)(1 - sp1) + cur;
                    int s = (hm >= 0.5) ? 1 : 0;
                    int n = s + sp1 + sp2;       // STDP window count after append
                    sp2 = sp1; sp1 = s;
                    naccr += (unsigned)n;
                    unsigned bit = 1u << (t & 31);
                    if (s)     curA  |= bit;
                    if (n & 1) curN0 |= bit;
                    if (n & 2) curN1 |= bit;
                    if ((t & 31) == 31) {
                        const int wq = t >> 5;
                        AwP [wq * HN + c] = curA;
                        N0wP[wq * HN + c] = curN0;
                        N1wP[wq * HN + c] = curN1;
                        curA = curN0 = curN1 = 0u;
                    }
                    unsigned long long ball = __ballot(s != 0);
                    if (lane == 0) {
                        __hip_atomic_store(&spk[(size_t)(t & 1) * 64 + wg * 4 + wv], ball,
                                           __ATOMIC_RELEASE, __HIP_MEMORY_SCOPE_AGENT);
                        __threadfence();       // drain before barrier arrival
                        s_wcnt[wv] = __popcll(ball);
                    }
                    if (t == TT - 1) Nacc[c] = naccr;
                    if (it + 1 < TT) ffv = ff[(size_t)(it + 1) * HN + c];  // prefetch
                } else {
                    const int t = it - 1;
                    om = om * 0.96 * (double)(1 - osp) + drive;
                    osp = (om >= 0.5) ? 1 : 0;
                    out[(size_t)t * NOUTC + c] = osp ? 1.0f : 0.0f;
                }
            }
        }
        // ---- grid barrier carrying the global spike count ------------------
        if (it < TT) {
            __syncthreads();
            if (tid == 0) {
                unsigned s = lsense ^ 1u;
                lsense = s;
                unsigned cntW = isH ? (unsigned)(s_wcnt[0] + s_wcnt[1] + s_wcnt[2] + s_wcnt[3]) : 0u;
                unsigned long long prev = __hip_atomic_fetch_add(
                    &bar[0], (1ULL << 32) + (unsigned long long)cntW,
                    __ATOMIC_ACQ_REL, __HIP_MEMORY_SCOPE_AGENT);
                unsigned long long v;
                if ((unsigned)(prev >> 32) == NWGT - 1u) {
                    unsigned ktot = (unsigned)(prev & 0xffffffffULL) + cntW;
                    __hip_atomic_store(&bar[0], 0ULL, __ATOMIC_RELAXED, __HIP_MEMORY_SCOPE_AGENT);
                    v = ((unsigned long long)ktot << 1) | (unsigned long long)s;
                    __hip_atomic_store(&bar[1], v, __ATOMIC_RELEASE, __HIP_MEMORY_SCOPE_AGENT);
                } else {
                    int budget = 1 << 17;   // bounded: never hang the GPU
                    for (;;) {
                        v = __hip_atomic_load(&bar[1], __ATOMIC_RELAXED, __HIP_MEMORY_SCOPE_AGENT);
                        if ((unsigned)(v & 1ULL) == s) {
                            v = __hip_atomic_load(&bar[1], __ATOMIC_ACQUIRE, __HIP_MEMORY_SCOPE_AGENT);
                            break;
                        }
                        if (--budget == 0) break;
                    }
                }
                s_kbc = (int)(v >> 1);
            }
            __syncthreads();
            kcur = s_kbc;
        }
    }
}

// ---------------- K5: rec_out = recurrent + 0.01*(3T - 2N[i] + 2M[i][j]) ----
__global__ __launch_bounds__(256) void k_rec(const float* __restrict__ recur,
    const unsigned* __restrict__ AwP, const unsigned* __restrict__ N0wP,
    const unsigned* __restrict__ N1wP, const unsigned* __restrict__ Nacc,
    float* __restrict__ out)
{
    const int j = blockIdx.x * 256 + threadIdx.x;
    const int i0 = blockIdx.y * 32;
    const unsigned a0 = AwP[0 * HN + j], a1 = AwP[1 * HN + j];
    const unsigned a2 = AwP[2 * HN + j], a3 = AwP[3 * HN + j];
    for (int ii = 0; ii < 32; ++ii) {
        const int i = i0 + ii;
        const unsigned n00 = N0wP[0 * HN + i], n01 = N0wP[1 * HN + i];
        const unsigned n02 = N0wP[2 * HN + i], n03 = N0wP[3 * HN + i];
        const unsigned n10 = N1wP[0 * HN + i], n11 = N1wP[1 * HN + i];
        const unsigned n12 = N1wP[2 * HN + i], n13 = N1wP[3 * HN + i];
        int M = __popc(a0 & n00) + __popc(a1 & n01) + __popc(a2 & n02) + __popc(a3 & n03);
        M += 2 * (__popc(a0 & n10) + __popc(a1 & n11) + __popc(a2 & n12) + __popc(a3 & n13));
        const int D = 3 * TT - 2 * (int)Nacc[i] + 2 * M;
        out[(size_t)i * HN + j] = (float)((double)recur[(size_t)i * HN + j] + 0.01 * (double)D);
    }
}

// ---------------- host ------------------------------------------------------
extern "C" void kernel_launch(void* const* d_in, const int* in_sizes, int n_in,
                              void* d_out, int out_size, void* d_ws, size_t ws_size,
                              hipStream_t stream) {
    const float* x         = (const float*)d_in[0];
    const float* w_fc1     = (const float*)d_in[1];
    const float* w_out     = (const float*)d_in[2];
    const float* recurrent = (const float*)d_in[3];
    const float* tau       = (const float*)d_in[4];
    const float* mask      = (const float*)d_in[5];
    const float* binary    = (const float*)d_in[6];
    float* out = (float*)d_out;
    float* rec_out = out + (size_t)TT * NOUTC;   // [HN,HN] region of d_out
    float* eff = rec_out;                         // reused as eff_rec scratch

    char* ws = (char*)d_ws;
    size_t off = 0;
    float* wT  = (float*)(ws + off);                 off += (size_t)HN * NOUTC * 4;   // 4MB
    double* ff = (double*)(ws + off);                off += (size_t)TT * HN * 8;      // 4MB
    // zero-span (contiguous): spk, bar
    unsigned long long* spk = (unsigned long long*)(ws + off); off += 2 * 64 * 8;     // 1KB
    unsigned long long* bar = (unsigned long long*)(ws + off); off += 256;
    const int zwords = (int)((2 * 64 * 8 + 256) / 4);
    unsigned* AwP  = (unsigned*)(ws + off);          off += (size_t)4 * HN * 4;       // 64KB
    unsigned* N0wP = (unsigned*)(ws + off);          off += (size_t)4 * HN * 4;
    unsigned* N1wP = (unsigned*)(ws + off);          off += (size_t)4 * HN * 4;
    unsigned* Nacc = (unsigned*)(ws + off);          off += (size_t)HN * 4;
    double* colP   = (double*)(ws + off);            off += (size_t)NRB * NCOLS * 8;  // 557KB

    if (ws_size < off) return;  // refuse to corrupt memory if scratch too small

    k_eff_zero<<<dim3(2049), dim3(256), 0, stream>>>(
        (const float4*)recurrent, (const float4*)mask, (const float4*)binary,
        (float4*)eff, (unsigned*)spk, zwords);
    k_transpose<<<dim3(64, 4), dim3(256), 0, stream>>>(w_out, wT);
    k_ff<<<dim3(32, 8), dim3(256), 0, stream>>>(x, w_fc1, ff);
    k_colsum<<<dim3(17, NRB), dim3(256), 0, stream>>>(eff, wT, colP);
    k_loop<<<dim3(NWGT), dim3(1024), 0, stream>>>(eff, wT, ff, tau, colP,
                                                  spk, AwP, N0wP, N1wP, Nacc, bar, out);
    k_rec<<<dim3(16, 128), dim3(256), 0, stream>>>(recurrent, AwP, N0wP, N1wP, Nacc,
                                                   rec_out);
}

// Round 6
// 488.988 us; speedup vs baseline: 2.9956x; 1.6846x over previous
//
#include <hip/hip_runtime.h>
#include <cstdint>
#include <cstddef>

#define HN    4096
#define TT    128
#define NIN   1024
#define NOUTC 256
#define NWGH  16            // hidden WGs in k_loopA, 256 columns each (4 update waves)
#define NWGO  1             // output WG in k_loopA
#define NWGT  (NWGH + NWGO)
#define NCOLS (HN + NOUTC)  // colsum table width
#define NRB   16            // row-blocks in k_colsum
#define S_A   12            // steps simulated by k_loopA (transient window)

// -------- K1: eff = recurrent*mask*binary (into d_out rec region) + zero sync span
__global__ __launch_bounds__(256) void k_eff_zero(
    const float4* __restrict__ r4, const float4* __restrict__ m4,
    const float4* __restrict__ b4, float4* __restrict__ e4,
    unsigned* __restrict__ zbase, int zwords)
{
    if (blockIdx.x == gridDim.x - 1) {
        for (int i = threadIdx.x; i < zwords; i += 256) zbase[i] = 0u;
        return;
    }
    const size_t n4 = (size_t)HN * HN / 4;
    const size_t stride = (size_t)(gridDim.x - 1) * 256;
    for (size_t i = (size_t)blockIdx.x * 256 + threadIdx.x; i < n4; i += stride) {
        float4 a = r4[i], b = m4[i], c = b4[i];
        float4 o;
        o.x = a.x * b.x * c.x;
        o.y = a.y * b.y * c.y;
        o.z = a.z * b.z * c.z;
        o.w = a.w * b.w * c.w;
        e4[i] = o;
    }
}

// ---------------- K2: w_outT[h][o] = w_out[o][h] ----------------------------
__global__ __launch_bounds__(256) void k_transpose(const float* __restrict__ wout,
                                                   float* __restrict__ wT)
{
    __shared__ float tile[64][65];
    const int h0 = blockIdx.x * 64;
    const int o0 = blockIdx.y * 64;
    const int lx = threadIdx.x & 63, ly = threadIdx.x >> 6;  // ly 0..3
    #pragma unroll
    for (int i = 0; i < 16; ++i) {
        int o = ly + 4 * i;
        tile[o][lx] = wout[(size_t)(o0 + o) * HN + h0 + lx];
    }
    __syncthreads();
    #pragma unroll
    for (int i = 0; i < 16; ++i) {
        int h = ly + 4 * i;
        wT[(size_t)(h0 + h) * NOUTC + o0 + lx] = tile[lx][h];
    }
}

// ---------------- K3: ff[t][h] = sum_i x[t][i]*w_fc1[h][i]  (fp64 acc) ------
__global__ __launch_bounds__(256) void k_ff(const float* __restrict__ x,
                                            const float* __restrict__ w,
                                            double* __restrict__ ff)
{
    __shared__ float xs[16][36];
    __shared__ float wsT[32][129];
    const int h0 = blockIdx.x * 128;
    const int t0 = blockIdx.y * 16;
    const int tid = threadIdx.x;
    const int tq = tid >> 5, hq = tid & 31;
    double acc[2][4] = {};
    for (int kc = 0; kc < NIN; kc += 32) {
        __syncthreads();
        #pragma unroll
        for (int s2 = 0; s2 < 2; ++s2) {
            int e = tid + s2 * 256; int t = e >> 5, k = e & 31;
            xs[t][k] = x[(size_t)(t0 + t) * NIN + kc + k];
        }
        #pragma unroll
        for (int s2 = 0; s2 < 16; ++s2) {
            int e = tid + s2 * 256; int h = e >> 5, k = e & 31;
            wsT[k][h] = w[(size_t)(h0 + h) * NIN + kc + k];
        }
        __syncthreads();
        #pragma unroll 8
        for (int k = 0; k < 32; ++k) {
            double a0 = (double)xs[tq][k];
            double a1 = (double)xs[tq + 8][k];
            double b0 = (double)wsT[k][hq];
            double b1 = (double)wsT[k][hq + 32];
            double b2 = (double)wsT[k][hq + 64];
            double b3 = (double)wsT[k][hq + 96];
            acc[0][0] += a0 * b0; acc[0][1] += a0 * b1; acc[0][2] += a0 * b2; acc[0][3] += a0 * b3;
            acc[1][0] += a1 * b0; acc[1][1] += a1 * b1; acc[1][2] += a1 * b2; acc[1][3] += a1 * b3;
        }
    }
    #pragma unroll
    for (int i = 0; i < 2; ++i)
        #pragma unroll
        for (int j = 0; j < 4; ++j)
            ff[(size_t)(t0 + tq + 8 * i) * HN + h0 + hq + 32 * j] = acc[i][j];
}

// ---------------- K3b: deterministic column partial sums --------------------
__global__ __launch_bounds__(256) void k_colsum(const float* __restrict__ eff,
                                                const float* __restrict__ wT,
                                                double* __restrict__ colP)
{
    const int bx = blockIdx.x, by = blockIdx.y, t = threadIdx.x;
    double s = 0.0;
    if (bx < 16) {
        const float* p = eff + (size_t)by * 256 * HN + bx * 256 + t;
        #pragma unroll 8
        for (int r = 0; r < 256; ++r) s += (double)p[(size_t)r * HN];
        colP[(size_t)by * NCOLS + bx * 256 + t] = s;
    } else {
        const float* p = wT + (size_t)by * 256 * NOUTC + t;
        #pragma unroll 8
        for (int r = 0; r < 256; ++r) s += (double)p[(size_t)r * NOUTC];
        colP[(size_t)by * NCOLS + HN + t] = s;
    }
}

// ---------------- K4a: multi-WG transient scan, steps 0..S_A-1 --------------
__global__ __launch_bounds__(1024) void k_loopA(
    const float* __restrict__ eff, const float* __restrict__ wT,
    const double* __restrict__ ff, const float* __restrict__ tau,
    const double* __restrict__ colP,
    unsigned long long* spk, unsigned long long* bar, float* out,
    double* __restrict__ hmS, unsigned* __restrict__ flagsS,
    unsigned* __restrict__ AS, unsigned* __restrict__ N0S, unsigned* __restrict__ N1S,
    double* __restrict__ omS, unsigned* __restrict__ oflagsS)
{
    __shared__ unsigned short s_list[2048];
    __shared__ double s_part[16][256];
    __shared__ int s_wcnt[4];
    __shared__ int s_kbc;

    const int wg = blockIdx.x;
    const int tid = threadIdx.x;
    const int wv = tid >> 6;
    const int lane = tid & 63;
    const bool isH = (wg < NWGH);

    const size_t rstride = isH ? (size_t)HN : (size_t)NOUTC;
    const int base0 = isH ? wg * 256 : 0;
    const float* gbase = (isH ? eff : wT) + base0 + lane;
    const int c = base0 + wv * 64 + lane;   // update-wave column (wv<4)

    double colv = 0.0, hm = 0.0, om = 0.0, ffv = 0.0;
    float tauv = 0.f;
    int sp1 = 0, sp2 = 0, osp = 0;
    unsigned curA = 0, curN0 = 0, curN1 = 0, naccr = 0;
    if (wv < 4) {
        const int ci = isH ? c : (HN + c);
        #pragma unroll
        for (int rb = 0; rb < NRB; ++rb) colv += colP[(size_t)rb * NCOLS + ci];
        if (isH) { tauv = tau[c]; ffv = ff[c]; }
    }
    unsigned lsense = 0;
    int kcur = 0;

    for (int it = 0; it <= S_A; ++it) {
        const bool active = isH ? (it < S_A) : (it > 0);
        if (active) {
            const int k = kcur;
            const bool gspk = (k <= HN / 2);
            const int nlist = gspk ? k : HN - k;
            if (nlist > 0) {
                if (tid < 64) {
                    unsigned long long w = __hip_atomic_load(
                        &spk[(size_t)((it + 1) & 1) * 64 + lane],
                        __ATOMIC_RELAXED, __HIP_MEMORY_SCOPE_AGENT);
                    unsigned long long myw = gspk ? w : ~w;
                    int cnt = __popcll(myw);
                    int incl = cnt;
                    #pragma unroll
                    for (int d = 1; d < 64; d <<= 1) {
                        int o = __shfl_up(incl, d, 64);
                        if (lane >= d) incl += o;
                    }
                    int b = incl - cnt;
                    while (myw) {
                        int bp = __builtin_ctzll(myw);
                        s_list[b++] = (unsigned short)(lane * 64 + bp);
                        myw &= myw - 1;
                    }
                }
                __syncthreads();
                double a0 = 0.0, a1 = 0.0, a2 = 0.0, a3 = 0.0;
                for (int idx = wv; idx < nlist; idx += 16) {
                    const float* rp = gbase + (size_t)s_list[idx] * rstride;
                    a0 += (double)rp[0];
                    a1 += (double)rp[64];
                    a2 += (double)rp[128];
                    a3 += (double)rp[192];
                }
                s_part[wv][lane] = a0;
                s_part[wv][64 + lane] = a1;
                s_part[wv][128 + lane] = a2;
                s_part[wv][192 + lane] = a3;
                __syncthreads();
            }
            if (wv < 4) {
                double ssum = 0.0;
                if (nlist > 0) {
                    const int j = wv * 64 + lane;
                    #pragma unroll
                    for (int p = 0; p < 16; ++p) ssum += s_part[p][j];
                }
                double drive = gspk ? ssum : (colv - ssum);
                if (isH) {
                    const int t = it;
                    double cur = ffv + 0.1 * drive;
                    hm = hm * (double)tauv * (double)(1 - sp1) + cur;
                    int s = (hm >= 0.5) ? 1 : 0;
                    int n = s + sp1 + sp2;
                    sp2 = sp1; sp1 = s;
                    naccr += (unsigned)n;
                    unsigned bit = 1u << (t & 31);
                    if (s)     curA  |= bit;
                    if (n & 1) curN0 |= bit;
                    if (n & 2) curN1 |= bit;
                    unsigned long long ball = __ballot(s != 0);
                    if (lane == 0) {
                        __hip_atomic_store(&spk[(size_t)(t & 1) * 64 + wg * 4 + wv], ball,
                                           __ATOMIC_RELEASE, __HIP_MEMORY_SCOPE_AGENT);
                        __threadfence();
                        s_wcnt[wv] = __popcll(ball);
                    }
                    ffv = ff[(size_t)(it + 1) * HN + c];  // prefetch (it+1 <= S_A valid)
                } else {
                    const int t = it - 1;
                    om = om * 0.96 * (double)(1 - osp) + drive;
                    osp = (om >= 0.5) ? 1 : 0;
                    out[(size_t)t * NOUTC + c] = osp ? 1.0f : 0.0f;
                }
            }
        }
        if (it < S_A) {
            __syncthreads();
            if (tid == 0) {
                unsigned s = lsense ^ 1u;
                lsense = s;
                unsigned cntW = isH ? (unsigned)(s_wcnt[0] + s_wcnt[1] + s_wcnt[2] + s_wcnt[3]) : 0u;
                unsigned long long prev = __hip_atomic_fetch_add(
                    &bar[0], (1ULL << 32) + (unsigned long long)cntW,
                    __ATOMIC_ACQ_REL, __HIP_MEMORY_SCOPE_AGENT);
                unsigned long long v;
                if ((unsigned)(prev >> 32) == NWGT - 1u) {
                    unsigned ktot = (unsigned)(prev & 0xffffffffULL) + cntW;
                    __hip_atomic_store(&bar[0], 0ULL, __ATOMIC_RELAXED, __HIP_MEMORY_SCOPE_AGENT);
                    v = ((unsigned long long)ktot << 1) | (unsigned long long)s;
                    __hip_atomic_store(&bar[1], v, __ATOMIC_RELEASE, __HIP_MEMORY_SCOPE_AGENT);
                } else {
                    int budget = 1 << 17;
                    for (;;) {
                        v = __hip_atomic_load(&bar[1], __ATOMIC_ACQUIRE, __HIP_MEMORY_SCOPE_AGENT);
                        if ((unsigned)(v & 1ULL) == s) break;
                        if (--budget == 0) break;
                    }
                }
                s_kbc = (int)(v >> 1);
            }
            __syncthreads();
            kcur = s_kbc;
        }
    }
    // ---- state dump for k_loopB ----
    if (wv < 4) {
        if (isH) {
            hmS[c] = hm;
            flagsS[c] = (unsigned)sp1 | ((unsigned)sp2 << 1) | (naccr << 2);
            AS[c] = curA; N0S[c] = curN0; N1S[c] = curN1;
        } else {
            omS[c] = om;
            oflagsS[c] = (unsigned)osp;
        }
    }
}

// ---------------- K4b: single-WG barrier-free scan, steps S_A..127 ----------
// 1 WG x 1024 threads; thread owns hidden neurons tid+1024p (p=0..3) and, for
// tid<256, output neuron tid. All inter-neuron traffic via LDS.
__global__ __launch_bounds__(1024) void k_loopB(
    const float* __restrict__ eff, const float* __restrict__ wT,
    const double* __restrict__ ff, const float* __restrict__ tau,
    const double* __restrict__ colP,
    const unsigned long long* __restrict__ spk,
    const double* __restrict__ hmS, const unsigned* __restrict__ flagsS,
    const unsigned* __restrict__ AS, const unsigned* __restrict__ N0S,
    const unsigned* __restrict__ N1S,
    const double* __restrict__ omS, const unsigned* __restrict__ oflagsS,
    unsigned* __restrict__ AwP, unsigned* __restrict__ N0wP,
    unsigned* __restrict__ N1wP, unsigned* __restrict__ Nacc,
    float* __restrict__ out)
{
    __shared__ unsigned long long s_words[64];
    __shared__ unsigned short s_list[2048];

    const int tid = threadIdx.x;
    const int wv = tid >> 6, lane = tid & 63;

    double hm[4], colv[4], tauv[4];
    unsigned curA[4], curN0[4], curN1[4], nacc[4];
    int sp1[4], sp2[4];
    #pragma unroll
    for (int p = 0; p < 4; ++p) {
        const int c = tid + 1024 * p;
        hm[p] = hmS[c];
        unsigned f = flagsS[c];
        sp1[p] = f & 1; sp2[p] = (f >> 1) & 1; nacc[p] = f >> 2;
        curA[p] = AS[c]; curN0[p] = N0S[c]; curN1[p] = N1S[c];
        tauv[p] = (double)tau[c];
        double cs = 0.0;
        #pragma unroll
        for (int rb = 0; rb < NRB; ++rb) cs += colP[(size_t)rb * NCOLS + c];
        colv[p] = cs;
    }
    double om = 0.0, colO = 0.0;
    int osp = 0;
    if (tid < NOUTC) {
        om = omS[tid]; osp = (int)(oflagsS[tid] & 1u);
        #pragma unroll
        for (int rb = 0; rb < NRB; ++rb) colO += colP[(size_t)rb * NCOLS + HN + tid];
    }

    // seed spike state from A's last step (parity (S_A-1)&1)
    if (tid < 64) s_words[tid] = spk[(size_t)((S_A - 1) & 1) * 64 + tid];
    __syncthreads();
    int kprev;
    {
        int v = __popcll(s_words[lane]);
        #pragma unroll
        for (int d = 1; d < 64; d <<= 1) v += __shfl_xor(v, d, 64);
        kprev = v;
    }
    bool gprev = (kprev <= HN / 2);
    int nprev = gprev ? kprev : HN - kprev;
    if (nprev > 0) {
        if (tid < 64) {
            unsigned long long myw = gprev ? s_words[tid] : ~s_words[tid];
            int cnt = __popcll(myw), incl = cnt;
            #pragma unroll
            for (int d = 1; d < 64; d <<= 1) { int o = __shfl_up(incl, d, 64); if (lane >= d) incl += o; }
            int b = incl - cnt;
            while (myw) { int bp = __builtin_ctzll(myw); s_list[b++] = (unsigned short)(tid * 64 + bp); myw &= myw - 1; }
        }
        __syncthreads();
    }

    double fnext[4];
    #pragma unroll
    for (int p = 0; p < 4; ++p) fnext[p] = ff[(size_t)S_A * HN + tid + 1024 * p];

    for (int t = S_A; t < TT; ++t) {
        // 1. hidden drive from previous step's list
        double fcur[4];
        #pragma unroll
        for (int p = 0; p < 4; ++p) fcur[p] = fnext[p];
        if (t + 1 < TT) {
            #pragma unroll
            for (int p = 0; p < 4; ++p) fnext[p] = ff[(size_t)(t + 1) * HN + tid + 1024 * p];
        }
        double drv[4];
        if (nprev > 0) {
            double s0 = 0.0, s1 = 0.0, s2 = 0.0, s3 = 0.0;
            for (int idx = 0; idx < nprev; ++idx) {
                const float* rp = eff + (size_t)s_list[idx] * HN + tid;
                s0 += (double)rp[0];
                s1 += (double)rp[1024];
                s2 += (double)rp[2048];
                s3 += (double)rp[3072];
            }
            drv[0] = gprev ? s0 : (colv[0] - s0);
            drv[1] = gprev ? s1 : (colv[1] - s1);
            drv[2] = gprev ? s2 : (colv[2] - s2);
            drv[3] = gprev ? s3 : (colv[3] - s3);
        } else {
            #pragma unroll
            for (int p = 0; p < 4; ++p) drv[p] = gprev ? 0.0 : colv[p];
        }
        // 2. membrane update + STDP bit accumulation
        int sb[4];
        const unsigned bit = 1u << (t & 31);
        #pragma unroll
        for (int p = 0; p < 4; ++p) {
            double cur = fcur[p] + 0.1 * drv[p];
            hm[p] = hm[p] * tauv[p] * (double)(1 - sp1[p]) + cur;
            sb[p] = (hm[p] >= 0.5) ? 1 : 0;
            int n = sb[p] + sp1[p] + sp2[p];
            sp2[p] = sp1[p]; sp1[p] = sb[p];
            nacc[p] += (unsigned)n;
            if (sb[p]) curA[p] |= bit;
            if (n & 1) curN0[p] |= bit;
            if (n & 2) curN1[p] |= bit;
        }
        if ((t & 31) == 31) {
            const int wq = t >> 5;
            #pragma unroll
            for (int p = 0; p < 4; ++p) {
                const int c = tid + 1024 * p;
                AwP [wq * HN + c] = curA[p];
                N0wP[wq * HN + c] = curN0[p];
                N1wP[wq * HN + c] = curN1[p];
                curA[p] = curN0[p] = curN1[p] = 0u;
            }
        }
        __syncthreads();   // everyone done reading s_words/s_list
        // 3. publish ballots
        #pragma unroll
        for (int p = 0; p < 4; ++p) {
            unsigned long long b = __ballot(sb[p] != 0);
            if (lane == 0) s_words[16 * p + wv] = b;
        }
        __syncthreads();
        // 4. k-reduce (every wave redundantly)
        int k;
        {
            int v = __popcll(s_words[lane]);
            #pragma unroll
            for (int d = 1; d < 64; d <<= 1) v += __shfl_xor(v, d, 64);
            k = v;
        }
        const bool gspk = (k <= HN / 2);
        const int nlist = gspk ? k : HN - k;
        // 5. build list (for this step's output gather and next step's hidden gather)
        if (nlist > 0) {
            if (tid < 64) {
                unsigned long long myw = gspk ? s_words[tid] : ~s_words[tid];
                int cnt = __popcll(myw), incl = cnt;
                #pragma unroll
                for (int d = 1; d < 64; d <<= 1) { int o = __shfl_up(incl, d, 64); if (lane >= d) incl += o; }
                int b2 = incl - cnt;
                while (myw) { int bp = __builtin_ctzll(myw); s_list[b2++] = (unsigned short)(tid * 64 + bp); myw &= myw - 1; }
            }
            __syncthreads();
        }
        // 6. output layer (uses CURRENT step's spikes)
        if (tid < NOUTC) {
            double so = 0.0;
            for (int idx = 0; idx < nlist; ++idx)
                so += (double)wT[(size_t)s_list[idx] * NOUTC + tid];
            double drv_o = gspk ? so : (colO - so);
            om = om * 0.96 * (double)(1 - osp) + drv_o;
            osp = (om >= 0.5) ? 1 : 0;
            out[(size_t)t * NOUTC + tid] = osp ? 1.0f : 0.0f;
        }
        kprev = k; gprev = gspk; nprev = nlist;
    }
    #pragma unroll
    for (int p = 0; p < 4; ++p) Nacc[tid + 1024 * p] = nacc[p];
}

// ---------------- K5: rec_out = recurrent + 0.01*(3T - 2N[i] + 2M[i][j]) ----
__global__ __launch_bounds__(256) void k_rec(const float* __restrict__ recur,
    const unsigned* __restrict__ AwP, const unsigned* __restrict__ N0wP,
    const unsigned* __restrict__ N1wP, const unsigned* __restrict__ Nacc,
    float* __restrict__ out)
{
    const int j = blockIdx.x * 256 + threadIdx.x;
    const int i0 = blockIdx.y * 32;
    const unsigned a0 = AwP[0 * HN + j], a1 = AwP[1 * HN + j];
    const unsigned a2 = AwP[2 * HN + j], a3 = AwP[3 * HN + j];
    for (int ii = 0; ii < 32; ++ii) {
        const int i = i0 + ii;
        const unsigned n00 = N0wP[0 * HN + i], n01 = N0wP[1 * HN + i];
        const unsigned n02 = N0wP[2 * HN + i], n03 = N0wP[3 * HN + i];
        const unsigned n10 = N1wP[0 * HN + i], n11 = N1wP[1 * HN + i];
        const unsigned n12 = N1wP[2 * HN + i], n13 = N1wP[3 * HN + i];
        int M = __popc(a0 & n00) + __popc(a1 & n01) + __popc(a2 & n02) + __popc(a3 & n03);
        M += 2 * (__popc(a0 & n10) + __popc(a1 & n11) + __popc(a2 & n12) + __popc(a3 & n13));
        const int D = 3 * TT - 2 * (int)Nacc[i] + 2 * M;
        out[(size_t)i * HN + j] = (float)((double)recur[(size_t)i * HN + j] + 0.01 * (double)D);
    }
}

// ---------------- host ------------------------------------------------------
extern "C" void kernel_launch(void* const* d_in, const int* in_sizes, int n_in,
                              void* d_out, int out_size, void* d_ws, size_t ws_size,
                              hipStream_t stream) {
    const float* x         = (const float*)d_in[0];
    const float* w_fc1     = (const float*)d_in[1];
    const float* w_out     = (const float*)d_in[2];
    const float* recurrent = (const float*)d_in[3];
    const float* tau       = (const float*)d_in[4];
    const float* mask      = (const float*)d_in[5];
    const float* binary    = (const float*)d_in[6];
    float* out = (float*)d_out;
    float* rec_out = out + (size_t)TT * NOUTC;   // [HN,HN] region of d_out
    float* eff = rec_out;                         // reused as eff_rec scratch

    char* ws = (char*)d_ws;
    size_t off = 0;
    float* wT  = (float*)(ws + off);                 off += (size_t)HN * NOUTC * 4;   // 4MB
    double* ff = (double*)(ws + off);                off += (size_t)TT * HN * 8;      // 4MB
    // zero-span (contiguous): spk, bar
    unsigned long long* spk = (unsigned long long*)(ws + off); off += 2 * 64 * 8;     // 1KB
    unsigned long long* bar = (unsigned long long*)(ws + off); off += 256;
    const int zwords = (int)((2 * 64 * 8 + 256) / 4);
    unsigned* AwP  = (unsigned*)(ws + off);          off += (size_t)4 * HN * 4;       // 64KB
    unsigned* N0wP = (unsigned*)(ws + off);          off += (size_t)4 * HN * 4;
    unsigned* N1wP = (unsigned*)(ws + off);          off += (size_t)4 * HN * 4;
    unsigned* Nacc = (unsigned*)(ws + off);          off += (size_t)HN * 4;
    double* colP   = (double*)(ws + off);            off += (size_t)NRB * NCOLS * 8;  // 557KB
    // A→B handoff state
    double*   hmS    = (double*)(ws + off);          off += (size_t)HN * 8;           // 32KB
    unsigned* flagsS = (unsigned*)(ws + off);        off += (size_t)HN * 4;           // 16KB
    unsigned* AS     = (unsigned*)(ws + off);        off += (size_t)HN * 4;
    unsigned* N0S    = (unsigned*)(ws + off);        off += (size_t)HN * 4;
    unsigned* N1S    = (unsigned*)(ws + off);        off += (size_t)HN * 4;
    double*   omS    = (double*)(ws + off);          off += (size_t)NOUTC * 8;        // 2KB
    unsigned* oflagsS= (unsigned*)(ws + off);        off += (size_t)NOUTC * 4;        // 1KB

    if (ws_size < off) return;  // refuse to corrupt memory if scratch too small

    k_eff_zero<<<dim3(2049), dim3(256), 0, stream>>>(
        (const float4*)recurrent, (const float4*)mask, (const float4*)binary,
        (float4*)eff, (unsigned*)spk, zwords);
    k_transpose<<<dim3(64, 4), dim3(256), 0, stream>>>(w_out, wT);
    k_ff<<<dim3(32, 8), dim3(256), 0, stream>>>(x, w_fc1, ff);
    k_colsum<<<dim3(17, NRB), dim3(256), 0, stream>>>(eff, wT, colP);
    k_loopA<<<dim3(NWGT), dim3(1024), 0, stream>>>(eff, wT, ff, tau, colP,
                                                   spk, bar, out,
                                                   hmS, flagsS, AS, N0S, N1S, omS, oflagsS);
    k_loopB<<<dim3(1), dim3(1024), 0, stream>>>(eff, wT, ff, tau, colP, spk,
                                                hmS, flagsS, AS, N0S, N1S, omS, oflagsS,
                                                AwP, N0wP, N1wP, Nacc, out);
    k_rec<<<dim3(16, 128), dim3(256), 0, stream>>>(recurrent, AwP, N0wP, N1wP, Nacc,
                                                   rec_out);
}

// Round 7
// 300.746 us; speedup vs baseline: 4.8707x; 1.6259x over previous
//
#include <hip/hip_runtime.h>
#include <cstdint>
#include <cstddef>

#define HN    4096
#define TT    128
#define NIN   1024
#define NOUTC 256
#define NWGH  16            // hidden WGs in k_loopA, 256 columns each (4 update waves)
#define NWGO  1             // output WG in k_loopA
#define NWGT  (NWGH + NWGO)
#define NCOLS (HN + NOUTC)  // colsum table width
#define NRB   16            // row-blocks in k_colsum
#define S_A   8             // steps simulated by k_loopA (transient window)

// -------- K1: eff = recurrent*mask*binary (into d_out rec region) + zero sync span
__global__ __launch_bounds__(256) void k_eff_zero(
    const float4* __restrict__ r4, const float4* __restrict__ m4,
    const float4* __restrict__ b4, float4* __restrict__ e4,
    unsigned* __restrict__ zbase, int zwords)
{
    if (blockIdx.x == gridDim.x - 1) {
        for (int i = threadIdx.x; i < zwords; i += 256) zbase[i] = 0u;
        return;
    }
    const size_t n4 = (size_t)HN * HN / 4;
    const size_t stride = (size_t)(gridDim.x - 1) * 256;
    for (size_t i = (size_t)blockIdx.x * 256 + threadIdx.x; i < n4; i += stride) {
        float4 a = r4[i], b = m4[i], c = b4[i];
        float4 o;
        o.x = a.x * b.x * c.x;
        o.y = a.y * b.y * c.y;
        o.z = a.z * b.z * c.z;
        o.w = a.w * b.w * c.w;
        e4[i] = o;
    }
}

// ---------------- K2: w_outT[h][o] = w_out[o][h] ----------------------------
__global__ __launch_bounds__(256) void k_transpose(const float* __restrict__ wout,
                                                   float* __restrict__ wT)
{
    __shared__ float tile[64][65];
    const int h0 = blockIdx.x * 64;
    const int o0 = blockIdx.y * 64;
    const int lx = threadIdx.x & 63, ly = threadIdx.x >> 6;  // ly 0..3
    #pragma unroll
    for (int i = 0; i < 16; ++i) {
        int o = ly + 4 * i;
        tile[o][lx] = wout[(size_t)(o0 + o) * HN + h0 + lx];
    }
    __syncthreads();
    #pragma unroll
    for (int i = 0; i < 16; ++i) {
        int h = ly + 4 * i;
        wT[(size_t)(h0 + h) * NOUTC + o0 + lx] = tile[lx][h];
    }
}

// ---------------- K3: ff[t][h] = sum_i x[t][i]*w_fc1[h][i]  (fp64 acc) ------
__global__ __launch_bounds__(256) void k_ff(const float* __restrict__ x,
                                            const float* __restrict__ w,
                                            double* __restrict__ ff)
{
    __shared__ float xs[16][36];
    __shared__ float wsT[32][129];
    const int h0 = blockIdx.x * 128;
    const int t0 = blockIdx.y * 16;
    const int tid = threadIdx.x;
    const int tq = tid >> 5, hq = tid & 31;
    double acc[2][4] = {};
    for (int kc = 0; kc < NIN; kc += 32) {
        __syncthreads();
        #pragma unroll
        for (int s2 = 0; s2 < 2; ++s2) {
            int e = tid + s2 * 256; int t = e >> 5, k = e & 31;
            xs[t][k] = x[(size_t)(t0 + t) * NIN + kc + k];
        }
        #pragma unroll
        for (int s2 = 0; s2 < 16; ++s2) {
            int e = tid + s2 * 256; int h = e >> 5, k = e & 31;
            wsT[k][h] = w[(size_t)(h0 + h) * NIN + kc + k];
        }
        __syncthreads();
        #pragma unroll 8
        for (int k = 0; k < 32; ++k) {
            double a0 = (double)xs[tq][k];
            double a1 = (double)xs[tq + 8][k];
            double b0 = (double)wsT[k][hq];
            double b1 = (double)wsT[k][hq + 32];
            double b2 = (double)wsT[k][hq + 64];
            double b3 = (double)wsT[k][hq + 96];
            acc[0][0] += a0 * b0; acc[0][1] += a0 * b1; acc[0][2] += a0 * b2; acc[0][3] += a0 * b3;
            acc[1][0] += a1 * b0; acc[1][1] += a1 * b1; acc[1][2] += a1 * b2; acc[1][3] += a1 * b3;
        }
    }
    #pragma unroll
    for (int i = 0; i < 2; ++i)
        #pragma unroll
        for (int j = 0; j < 4; ++j)
            ff[(size_t)(t0 + tq + 8 * i) * HN + h0 + hq + 32 * j] = acc[i][j];
}

// ---------------- K3b: deterministic column partial sums --------------------
__global__ __launch_bounds__(256) void k_colsum(const float* __restrict__ eff,
                                                const float* __restrict__ wT,
                                                double* __restrict__ colP)
{
    const int bx = blockIdx.x, by = blockIdx.y, t = threadIdx.x;
    double s = 0.0;
    if (bx < 16) {
        const float* p = eff + (size_t)by * 256 * HN + bx * 256 + t;
        #pragma unroll 8
        for (int r = 0; r < 256; ++r) s += (double)p[(size_t)r * HN];
        colP[(size_t)by * NCOLS + bx * 256 + t] = s;
    } else {
        const float* p = wT + (size_t)by * 256 * NOUTC + t;
        #pragma unroll 8
        for (int r = 0; r < 256; ++r) s += (double)p[(size_t)r * NOUTC];
        colP[(size_t)by * NCOLS + HN + t] = s;
    }
}

// ---------------- K3c: reduce colP -> colvH (hidden cols, same order as loop)
__global__ __launch_bounds__(256) void k_colred(const double* __restrict__ colP,
                                                double* __restrict__ colvH)
{
    const int h = blockIdx.x * 256 + threadIdx.x;   // grid 16
    double s = 0.0;
    #pragma unroll
    for (int rb = 0; rb < NRB; ++rb) s += colP[(size_t)rb * NCOLS + h];
    colvH[h] = s;
}

// ---------------- K3d: saturation predicate for steps S_A..TT-1 -------------
// sat[t] = AND_h ( ff[t,h] + 0.1*colv[h] >= 0.5 )  -- bit-identical expression
// to the scan's all-spike membrane update. Fail -> satFail |= 1 (deterministic).
__global__ __launch_bounds__(256) void k_sat(const double* __restrict__ ff,
                                             const double* __restrict__ colvH,
                                             unsigned* __restrict__ satFail)
{
    __shared__ int s_ok[4];
    const int t = S_A + blockIdx.x;
    const int tid = threadIdx.x;
    bool ok = true;
    #pragma unroll
    for (int i = 0; i < 16; ++i) {
        const int h = tid + 256 * i;
        ok = ok && ((ff[(size_t)t * HN + h] + 0.1 * colvH[h]) >= 0.5);
    }
    unsigned long long b = __ballot(ok);
    if ((tid & 63) == 0) s_ok[tid >> 6] = (b == ~0ULL) ? 1 : 0;
    __syncthreads();
    if (tid == 0) {
        if (!(s_ok[0] & s_ok[1] & s_ok[2] & s_ok[3])) atomicOr(satFail, 1u);
    }
}

// ---------------- K4a: multi-WG transient scan, steps 0..S_A-1 --------------
__global__ __launch_bounds__(1024) void k_loopA(
    const float* __restrict__ eff, const float* __restrict__ wT,
    const double* __restrict__ ff, const float* __restrict__ tau,
    const double* __restrict__ colP,
    unsigned long long* spk, unsigned long long* bar, float* out,
    double* __restrict__ hmS, unsigned* __restrict__ flagsS,
    unsigned* __restrict__ AS, unsigned* __restrict__ N0S, unsigned* __restrict__ N1S,
    double* __restrict__ omS, unsigned* __restrict__ oflagsS)
{
    __shared__ unsigned short s_list[2048];
    __shared__ double s_part[16][256];
    __shared__ int s_wcnt[4];
    __shared__ int s_kbc;

    const int wg = blockIdx.x;
    const int tid = threadIdx.x;
    const int wv = tid >> 6;
    const int lane = tid & 63;
    const bool isH = (wg < NWGH);

    const size_t rstride = isH ? (size_t)HN : (size_t)NOUTC;
    const int base0 = isH ? wg * 256 : 0;
    const float* gbase = (isH ? eff : wT) + base0 + lane;
    const int c = base0 + wv * 64 + lane;   // update-wave column (wv<4)

    double colv = 0.0, hm = 0.0, om = 0.0, ffv = 0.0;
    float tauv = 0.f;
    int sp1 = 0, sp2 = 0, osp = 0;
    unsigned curA = 0, curN0 = 0, curN1 = 0, naccr = 0;
    if (wv < 4) {
        const int ci = isH ? c : (HN + c);
        #pragma unroll
        for (int rb = 0; rb < NRB; ++rb) colv += colP[(size_t)rb * NCOLS + ci];
        if (isH) { tauv = tau[c]; ffv = ff[c]; }
    }
    unsigned lsense = 0;
    int kcur = 0;

    for (int it = 0; it <= S_A; ++it) {
        const bool active = isH ? (it < S_A) : (it > 0);
        if (active) {
            const int k = kcur;
            const bool gspk = (k <= HN / 2);
            const int nlist = gspk ? k : HN - k;
            if (nlist > 0) {
                if (tid < 64) {
                    unsigned long long w = __hip_atomic_load(
                        &spk[(size_t)((it + 1) & 1) * 64 + lane],
                        __ATOMIC_RELAXED, __HIP_MEMORY_SCOPE_AGENT);
                    unsigned long long myw = gspk ? w : ~w;
                    int cnt = __popcll(myw);
                    int incl = cnt;
                    #pragma unroll
                    for (int d = 1; d < 64; d <<= 1) {
                        int o = __shfl_up(incl, d, 64);
                        if (lane >= d) incl += o;
                    }
                    int b = incl - cnt;
                    while (myw) {
                        int bp = __builtin_ctzll(myw);
                        s_list[b++] = (unsigned short)(lane * 64 + bp);
                        myw &= myw - 1;
                    }
                }
                __syncthreads();
                double a0 = 0.0, a1 = 0.0, a2 = 0.0, a3 = 0.0;
                for (int idx = wv; idx < nlist; idx += 16) {
                    const float* rp = gbase + (size_t)s_list[idx] * rstride;
                    a0 += (double)rp[0];
                    a1 += (double)rp[64];
                    a2 += (double)rp[128];
                    a3 += (double)rp[192];
                }
                s_part[wv][lane] = a0;
                s_part[wv][64 + lane] = a1;
                s_part[wv][128 + lane] = a2;
                s_part[wv][192 + lane] = a3;
                __syncthreads();
            }
            if (wv < 4) {
                double ssum = 0.0;
                if (nlist > 0) {
                    const int j = wv * 64 + lane;
                    #pragma unroll
                    for (int p = 0; p < 16; ++p) ssum += s_part[p][j];
                }
                double drive = gspk ? ssum : (colv - ssum);
                if (isH) {
                    const int t = it;
                    double cur = ffv + 0.1 * drive;
                    hm = hm * (double)tauv * (double)(1 - sp1) + cur;
                    int s = (hm >= 0.5) ? 1 : 0;
                    int n = s + sp1 + sp2;
                    sp2 = sp1; sp1 = s;
                    naccr += (unsigned)n;
                    unsigned bit = 1u << (t & 31);
                    if (s)     curA  |= bit;
                    if (n & 1) curN0 |= bit;
                    if (n & 2) curN1 |= bit;
                    unsigned long long ball = __ballot(s != 0);
                    if (lane == 0) {
                        __hip_atomic_store(&spk[(size_t)(t & 1) * 64 + wg * 4 + wv], ball,
                                           __ATOMIC_RELEASE, __HIP_MEMORY_SCOPE_AGENT);
                        __threadfence();
                        s_wcnt[wv] = __popcll(ball);
                    }
                    ffv = ff[(size_t)(it + 1) * HN + c];  // prefetch (it+1 <= S_A valid)
                } else {
                    const int t = it - 1;
                    om = om * 0.96 * (double)(1 - osp) + drive;
                    osp = (om >= 0.5) ? 1 : 0;
                    out[(size_t)t * NOUTC + c] = osp ? 1.0f : 0.0f;
                }
            }
        }
        if (it < S_A) {
            __syncthreads();
            if (tid == 0) {
                unsigned s = lsense ^ 1u;
                lsense = s;
                unsigned cntW = isH ? (unsigned)(s_wcnt[0] + s_wcnt[1] + s_wcnt[2] + s_wcnt[3]) : 0u;
                unsigned long long prev = __hip_atomic_fetch_add(
                    &bar[0], (1ULL << 32) + (unsigned long long)cntW,
                    __ATOMIC_ACQ_REL, __HIP_MEMORY_SCOPE_AGENT);
                unsigned long long v;
                if ((unsigned)(prev >> 32) == NWGT - 1u) {
                    unsigned ktot = (unsigned)(prev & 0xffffffffULL) + cntW;
                    __hip_atomic_store(&bar[0], 0ULL, __ATOMIC_RELAXED, __HIP_MEMORY_SCOPE_AGENT);
                    v = ((unsigned long long)ktot << 1) | (unsigned long long)s;
                    __hip_atomic_store(&bar[1], v, __ATOMIC_RELEASE, __HIP_MEMORY_SCOPE_AGENT);
                } else {
                    int budget = 1 << 17;
                    for (;;) {
                        v = __hip_atomic_load(&bar[1], __ATOMIC_ACQUIRE, __HIP_MEMORY_SCOPE_AGENT);
                        if ((unsigned)(v & 1ULL) == s) break;
                        if (--budget == 0) break;
                    }
                }
                s_kbc = (int)(v >> 1);
            }
            __syncthreads();
            kcur = s_kbc;
        }
    }
    // ---- state dump for k_loopB ----
    if (wv < 4) {
        if (isH) {
            hmS[c] = hm;
            flagsS[c] = (unsigned)sp1 | ((unsigned)sp2 << 1) | (naccr << 2);
            AS[c] = curA; N0S[c] = curN0; N1S[c] = curN1;
        } else {
            omS[c] = om;
            oflagsS[c] = (unsigned)osp;
        }
    }
}

// ---------------- K4b: single-WG scan, steps S_A..127 -----------------------
// Fast path (saturation verified by k_sat + handoff k==HN): closed-form STDP
// words + 256-lane register-resident output recurrence. Slow path: general loop.
__global__ __launch_bounds__(1024) void k_loopB(
    const float* __restrict__ eff, const float* __restrict__ wT,
    const double* __restrict__ ff, const float* __restrict__ tau,
    const double* __restrict__ colP,
    const unsigned long long* __restrict__ spk,
    const double* __restrict__ hmS, const unsigned* __restrict__ flagsS,
    const unsigned* __restrict__ AS, const unsigned* __restrict__ N0S,
    const unsigned* __restrict__ N1S,
    const double* __restrict__ omS, const unsigned* __restrict__ oflagsS,
    const unsigned* __restrict__ satFail,
    unsigned* __restrict__ AwP, unsigned* __restrict__ N0wP,
    unsigned* __restrict__ N1wP, unsigned* __restrict__ Nacc,
    float* __restrict__ out)
{
    __shared__ unsigned long long s_words[64];
    __shared__ unsigned short s_list[2048];

    const int tid = threadIdx.x;
    const int wv = tid >> 6, lane = tid & 63;

    // seed spike state from A's last step (parity (S_A-1)&1)
    if (tid < 64) s_words[tid] = spk[(size_t)((S_A - 1) & 1) * 64 + tid];
    __syncthreads();
    int kprev;
    {
        int v = __popcll(s_words[lane]);
        #pragma unroll
        for (int d = 1; d < 64; d <<= 1) v += __shfl_xor(v, d, 64);
        kprev = v;
    }
    const bool fast = (satFail[0] == 0u) && (kprev == HN);

    if (fast) {
        // ---- hidden layer: closed form (s=1 for all t in [S_A,TT)) ---------
        #pragma unroll
        for (int p = 0; p < 4; ++p) {
            const int c = tid + 1024 * p;
            const unsigned f = flagsS[c];
            const int sp1 = (int)(f & 1u), sp2 = (int)((f >> 1) & 1u);
            const unsigned nacc0 = f >> 2;
            const int n8 = 1 + sp1 + sp2;    // step S_A
            const int n9 = 2 + sp1;          // step S_A+1 ; n=3 for t>=S_A+2
            AwP [0 * HN + c] = AS[c]  | (0xFFFFFFFFu << S_A);
            N0wP[0 * HN + c] = N0S[c] | ((unsigned)(n8 & 1) << S_A)
                                      | ((unsigned)(n9 & 1) << (S_A + 1))
                                      | (0xFFFFFFFFu << (S_A + 2));
            N1wP[0 * HN + c] = N1S[c] | ((unsigned)((n8 >> 1) & 1) << S_A)
                                      | ((unsigned)((n9 >> 1) & 1) << (S_A + 1))
                                      | (0xFFFFFFFFu << (S_A + 2));
            #pragma unroll
            for (int wq = 1; wq < 4; ++wq) {
                AwP [wq * HN + c] = 0xFFFFFFFFu;
                N0wP[wq * HN + c] = 0xFFFFFFFFu;
                N1wP[wq * HN + c] = 0xFFFFFFFFu;
            }
            Nacc[c] = nacc0 + (unsigned)n8 + (unsigned)n9 + 3u * (TT - S_A - 2);
        }
        // ---- output layer: scalar recurrence, drive = colO every step ------
        if (tid < NOUTC) {
            double om = omS[tid];
            int osp = (int)(oflagsS[tid] & 1u);
            double colO = 0.0;
            #pragma unroll
            for (int rb = 0; rb < NRB; ++rb) colO += colP[(size_t)rb * NCOLS + HN + tid];
            for (int t = S_A; t < TT; ++t) {
                om = om * 0.96 * (double)(1 - osp) + colO;
                osp = (om >= 0.5) ? 1 : 0;
                out[(size_t)t * NOUTC + tid] = osp ? 1.0f : 0.0f;
            }
        }
        return;
    }

    // ======================= slow path (general) ============================
    double hm[4], colv[4], tauv[4];
    unsigned curA[4], curN0[4], curN1[4], nacc[4];
    int sp1[4], sp2[4];
    #pragma unroll
    for (int p = 0; p < 4; ++p) {
        const int c = tid + 1024 * p;
        hm[p] = hmS[c];
        unsigned f = flagsS[c];
        sp1[p] = f & 1; sp2[p] = (f >> 1) & 1; nacc[p] = f >> 2;
        curA[p] = AS[c]; curN0[p] = N0S[c]; curN1[p] = N1S[c];
        tauv[p] = (double)tau[c];
        double cs = 0.0;
        #pragma unroll
        for (int rb = 0; rb < NRB; ++rb) cs += colP[(size_t)rb * NCOLS + c];
        colv[p] = cs;
    }
    double om = 0.0, colO = 0.0;
    int osp = 0;
    if (tid < NOUTC) {
        om = omS[tid]; osp = (int)(oflagsS[tid] & 1u);
        #pragma unroll
        for (int rb = 0; rb < NRB; ++rb) colO += colP[(size_t)rb * NCOLS + HN + tid];
    }
    bool gprev = (kprev <= HN / 2);
    int nprev = gprev ? kprev : HN - kprev;
    if (nprev > 0) {
        if (tid < 64) {
            unsigned long long myw = gprev ? s_words[tid] : ~s_words[tid];
            int cnt = __popcll(myw), incl = cnt;
            #pragma unroll
            for (int d = 1; d < 64; d <<= 1) { int o = __shfl_up(incl, d, 64); if (lane >= d) incl += o; }
            int b = incl - cnt;
            while (myw) { int bp = __builtin_ctzll(myw); s_list[b++] = (unsigned short)(tid * 64 + bp); myw &= myw - 1; }
        }
        __syncthreads();
    }

    double fnext[4];
    #pragma unroll
    for (int p = 0; p < 4; ++p) fnext[p] = ff[(size_t)S_A * HN + tid + 1024 * p];

    for (int t = S_A; t < TT; ++t) {
        double fcur[4];
        #pragma unroll
        for (int p = 0; p < 4; ++p) fcur[p] = fnext[p];
        if (t + 1 < TT) {
            #pragma unroll
            for (int p = 0; p < 4; ++p) fnext[p] = ff[(size_t)(t + 1) * HN + tid + 1024 * p];
        }
        double drv[4];
        if (nprev > 0) {
            double s0 = 0.0, s1 = 0.0, s2 = 0.0, s3 = 0.0;
            for (int idx = 0; idx < nprev; ++idx) {
                const float* rp = eff + (size_t)s_list[idx] * HN + tid;
                s0 += (double)rp[0];
                s1 += (double)rp[1024];
                s2 += (double)rp[2048];
                s3 += (double)rp[3072];
            }
            drv[0] = gprev ? s0 : (colv[0] - s0);
            drv[1] = gprev ? s1 : (colv[1] - s1);
            drv[2] = gprev ? s2 : (colv[2] - s2);
            drv[3] = gprev ? s3 : (colv[3] - s3);
        } else {
            #pragma unroll
            for (int p = 0; p < 4; ++p) drv[p] = gprev ? 0.0 : colv[p];
        }
        int sb[4];
        const unsigned bit = 1u << (t & 31);
        #pragma unroll
        for (int p = 0; p < 4; ++p) {
            double cur = fcur[p] + 0.1 * drv[p];
            hm[p] = hm[p] * tauv[p] * (double)(1 - sp1[p]) + cur;
            sb[p] = (hm[p] >= 0.5) ? 1 : 0;
            int n = sb[p] + sp1[p] + sp2[p];
            sp2[p] = sp1[p]; sp1[p] = sb[p];
            nacc[p] += (unsigned)n;
            if (sb[p]) curA[p] |= bit;
            if (n & 1) curN0[p] |= bit;
            if (n & 2) curN1[p] |= bit;
        }
        if ((t & 31) == 31) {
            const int wq = t >> 5;
            #pragma unroll
            for (int p = 0; p < 4; ++p) {
                const int c = tid + 1024 * p;
                AwP [wq * HN + c] = curA[p];
                N0wP[wq * HN + c] = curN0[p];
                N1wP[wq * HN + c] = curN1[p];
                curA[p] = curN0[p] = curN1[p] = 0u;
            }
        }
        __syncthreads();
        #pragma unroll
        for (int p = 0; p < 4; ++p) {
            unsigned long long b = __ballot(sb[p] != 0);
            if (lane == 0) s_words[16 * p + wv] = b;
        }
        __syncthreads();
        int k;
        {
            int v = __popcll(s_words[lane]);
            #pragma unroll
            for (int d = 1; d < 64; d <<= 1) v += __shfl_xor(v, d, 64);
            k = v;
        }
        const bool gspk = (k <= HN / 2);
        const int nlist = gspk ? k : HN - k;
        if (nlist > 0) {
            if (tid < 64) {
                unsigned long long myw = gspk ? s_words[tid] : ~s_words[tid];
                int cnt = __popcll(myw), incl = cnt;
                #pragma unroll
                for (int d = 1; d < 64; d <<= 1) { int o = __shfl_up(incl, d, 64); if (lane >= d) incl += o; }
                int b2 = incl - cnt;
                while (myw) { int bp = __builtin_ctzll(myw); s_list[b2++] = (unsigned short)(tid * 64 + bp); myw &= myw - 1; }
            }
            __syncthreads();
        }
        if (tid < NOUTC) {
            double so = 0.0;
            for (int idx = 0; idx < nlist; ++idx)
                so += (double)wT[(size_t)s_list[idx] * NOUTC + tid];
            double drv_o = gspk ? so : (colO - so);
            om = om * 0.96 * (double)(1 - osp) + drv_o;
            osp = (om >= 0.5) ? 1 : 0;
            out[(size_t)t * NOUTC + tid] = osp ? 1.0f : 0.0f;
        }
        kprev = k; gprev = gspk; nprev = nlist;
    }
    #pragma unroll
    for (int p = 0; p < 4; ++p) Nacc[tid + 1024 * p] = nacc[p];
}

// ---------------- K5: rec_out = recurrent + 0.01*(3T - 2N[i] + 2M[i][j]) ----
__global__ __launch_bounds__(256) void k_rec(const float* __restrict__ recur,
    const unsigned* __restrict__ AwP, const unsigned* __restrict__ N0wP,
    const unsigned* __restrict__ N1wP, const unsigned* __restrict__ Nacc,
    float* __restrict__ out)
{
    const int j = blockIdx.x * 256 + threadIdx.x;
    const int i0 = blockIdx.y * 32;
    const unsigned a0 = AwP[0 * HN + j], a1 = AwP[1 * HN + j];
    const unsigned a2 = AwP[2 * HN + j], a3 = AwP[3 * HN + j];
    for (int ii = 0; ii < 32; ++ii) {
        const int i = i0 + ii;
        const unsigned n00 = N0wP[0 * HN + i], n01 = N0wP[1 * HN + i];
        const unsigned n02 = N0wP[2 * HN + i], n03 = N0wP[3 * HN + i];
        const unsigned n10 = N1wP[0 * HN + i], n11 = N1wP[1 * HN + i];
        const unsigned n12 = N1wP[2 * HN + i], n13 = N1wP[3 * HN + i];
        int M = __popc(a0 & n00) + __popc(a1 & n01) + __popc(a2 & n02) + __popc(a3 & n03);
        M += 2 * (__popc(a0 & n10) + __popc(a1 & n11) + __popc(a2 & n12) + __popc(a3 & n13));
        const int D = 3 * TT - 2 * (int)Nacc[i] + 2 * M;
        out[(size_t)i * HN + j] = (float)((double)recur[(size_t)i * HN + j] + 0.01 * (double)D);
    }
}

// ---------------- host ------------------------------------------------------
extern "C" void kernel_launch(void* const* d_in, const int* in_sizes, int n_in,
                              void* d_out, int out_size, void* d_ws, size_t ws_size,
                              hipStream_t stream) {
    const float* x         = (const float*)d_in[0];
    const float* w_fc1     = (const float*)d_in[1];
    const float* w_out     = (const float*)d_in[2];
    const float* recurrent = (const float*)d_in[3];
    const float* tau       = (const float*)d_in[4];
    const float* mask      = (const float*)d_in[5];
    const float* binary    = (const float*)d_in[6];
    float* out = (float*)d_out;
    float* rec_out = out + (size_t)TT * NOUTC;   // [HN,HN] region of d_out
    float* eff = rec_out;                         // reused as eff_rec scratch

    char* ws = (char*)d_ws;
    size_t off = 0;
    float* wT  = (float*)(ws + off);                 off += (size_t)HN * NOUTC * 4;   // 4MB
    double* ff = (double*)(ws + off);                off += (size_t)TT * HN * 8;      // 4MB
    // zero-span (contiguous): spk, bar(+satFail)
    unsigned long long* spk = (unsigned long long*)(ws + off); off += 2 * 64 * 8;     // 1KB
    unsigned long long* bar = (unsigned long long*)(ws + off); off += 256;
    unsigned* satFail = (unsigned*)((char*)bar + 128);   // inside zeroed bar block
    const int zwords = (int)((2 * 64 * 8 + 256) / 4);
    unsigned* AwP  = (unsigned*)(ws + off);          off += (size_t)4 * HN * 4;       // 64KB
    unsigned* N0wP = (unsigned*)(ws + off);          off += (size_t)4 * HN * 4;
    unsigned* N1wP = (unsigned*)(ws + off);          off += (size_t)4 * HN * 4;
    unsigned* Nacc = (unsigned*)(ws + off);          off += (size_t)HN * 4;
    double* colP   = (double*)(ws + off);            off += (size_t)NRB * NCOLS * 8;  // 557KB
    double* colvH  = (double*)(ws + off);            off += (size_t)HN * 8;           // 32KB
    // A→B handoff state
    double*   hmS    = (double*)(ws + off);          off += (size_t)HN * 8;           // 32KB
    unsigned* flagsS = (unsigned*)(ws + off);        off += (size_t)HN * 4;           // 16KB
    unsigned* AS     = (unsigned*)(ws + off);        off += (size_t)HN * 4;
    unsigned* N0S    = (unsigned*)(ws + off);        off += (size_t)HN * 4;
    unsigned* N1S    = (unsigned*)(ws + off);        off += (size_t)HN * 4;
    double*   omS    = (double*)(ws + off);          off += (size_t)NOUTC * 8;        // 2KB
    unsigned* oflagsS= (unsigned*)(ws + off);        off += (size_t)NOUTC * 4;        // 1KB

    if (ws_size < off) return;  // refuse to corrupt memory if scratch too small

    k_eff_zero<<<dim3(2049), dim3(256), 0, stream>>>(
        (const float4*)recurrent, (const float4*)mask, (const float4*)binary,
        (float4*)eff, (unsigned*)spk, zwords);
    k_transpose<<<dim3(64, 4), dim3(256), 0, stream>>>(w_out, wT);
    k_ff<<<dim3(32, 8), dim3(256), 0, stream>>>(x, w_fc1, ff);
    k_colsum<<<dim3(17, NRB), dim3(256), 0, stream>>>(eff, wT, colP);
    k_colred<<<dim3(16), dim3(256), 0, stream>>>(colP, colvH);
    k_sat<<<dim3(TT - S_A), dim3(256), 0, stream>>>(ff, colvH, satFail);
    k_loopA<<<dim3(NWGT), dim3(1024), 0, stream>>>(eff, wT, ff, tau, colP,
                                                   spk, bar, out,
                                                   hmS, flagsS, AS, N0S, N1S, omS, oflagsS);
    k_loopB<<<dim3(1), dim3(1024), 0, stream>>>(eff, wT, ff, tau, colP, spk,
                                                hmS, flagsS, AS, N0S, N1S, omS, oflagsS,
                                                satFail, AwP, N0wP, N1wP, Nacc, out);
    k_rec<<<dim3(16, 128), dim3(256), 0, stream>>>(recurrent, AwP, N0wP, N1wP, Nacc,
                                                   rec_out);
}